// Round 1
// baseline (765.844 us; speedup 1.0000x reference)
//
#include <hip/hip_runtime.h>
#include <hip/hip_bf16.h>

#define D     128
#define NHEAD 8
#define FE    5
#define LSEQ  4096
#define EPB   16           // edges per block in edge_kernel
#define HNS   (EPB + 4)    // hn LDS row stride (float4-aligned)
#define EPS_LN 1e-5f
#define EPS_SM 1e-16f

// ---------------------------------------------------------------------------
// Simple row-tiled GEMM: Y[r][j] = sum_i X[r][i]*W[i][j] + b[j]
// block = 128 threads (j), 8 rows per block. W rows read coalesced, X row in LDS.
// ---------------------------------------------------------------------------
__global__ __launch_bounds__(128) void gemm128(
    const float* __restrict__ X, const float* __restrict__ W,
    const float* __restrict__ bias, float* __restrict__ Y)
{
    __shared__ float xs[8][D];
    const int j  = threadIdx.x;
    const int r0 = blockIdx.x * 8;
    #pragma unroll
    for (int r = 0; r < 8; ++r) xs[r][j] = X[(size_t)(r0 + r) * D + j];
    __syncthreads();
    float acc[8];
    const float b = bias[j];
    #pragma unroll
    for (int r = 0; r < 8; ++r) acc[r] = b;
    #pragma unroll 4
    for (int i = 0; i < D; ++i) {
        const float w = W[i * D + j];
        #pragma unroll
        for (int r = 0; r < 8; ++r) acc[r] = fmaf(xs[r][i], w, acc[r]);
    }
    #pragma unroll
    for (int r = 0; r < 8; ++r) Y[(size_t)(r0 + r) * D + j] = acc[r];
}

// ---------------------------------------------------------------------------
// Edge MLP helpers (operate on one block's EPB edges).
// hn layout: hn[dim * HNS + e]  (transposed, padded: conflict-light writes,
// float4 reads along e for the micro-tiled second layer)
// ---------------------------------------------------------------------------
__device__ __forceinline__ void first_ln(
    int t, const float ef[EPB][8], float* hn,
    const float* __restrict__ w1, const float* __restrict__ b1,
    const float* __restrict__ g,  const float* __restrict__ be,
    float part1[8][EPB], float part2[8][EPB], float* mu_s, float* rs_s)
{
    float w1f[FE];
    #pragma unroll
    for (int f = 0; f < FE; ++f) w1f[f] = w1[f * D + t];
    const float b1j = b1[t], gj = g[t], bej = be[t];
    #pragma unroll
    for (int e = 0; e < EPB; ++e) {
        float h = b1j;
        #pragma unroll
        for (int f = 0; f < FE; ++f) h = fmaf(ef[e][f], w1f[f], h);
        hn[t * HNS + e] = fmaxf(h, 0.f);
    }
    __syncthreads();
    {   // per-edge mean / mean-of-squares: 8 threads per edge, 16 dims each
        const int e = t & 15, grp = t >> 4;
        float s1 = 0.f, s2 = 0.f;
        #pragma unroll
        for (int i = 0; i < 16; ++i) {
            const float x = hn[(grp * 16 + i) * HNS + e];
            s1 += x; s2 += x * x;
        }
        part1[grp][e] = s1; part2[grp][e] = s2;
    }
    __syncthreads();
    if (t < EPB) {
        float s1 = 0.f, s2 = 0.f;
        #pragma unroll
        for (int p = 0; p < 8; ++p) { s1 += part1[p][t]; s2 += part2[p][t]; }
        const float mu  = s1 * (1.f / 128.f);
        const float var = s2 * (1.f / 128.f) - mu * mu;
        mu_s[t] = mu;
        rs_s[t] = rsqrtf(var + EPS_LN);
    }
    __syncthreads();
    #pragma unroll
    for (int e = 0; e < EPB; ++e) {
        const float x = hn[t * HNS + e];
        hn[t * HNS + e] = (x - mu_s[e]) * rs_s[e] * gj + bej;
    }
    __syncthreads();
}

// second layer D->D, 4x4 register micro-tile per thread
__device__ __forceinline__ void second_big(
    int t, const float* hn, const float* __restrict__ w2,
    const float* __restrict__ b2, float out2[EPB][D + 4])
{
    const int j0 = (t & 31) * 4;
    const int e0 = (t >> 5) * 4;
    float acc[4][4];
    #pragma unroll
    for (int eq = 0; eq < 4; ++eq)
        #pragma unroll
        for (int jq = 0; jq < 4; ++jq) acc[eq][jq] = 0.f;
    #pragma unroll 8
    for (int i = 0; i < D; ++i) {
        const float4 h4 = *reinterpret_cast<const float4*>(&hn[i * HNS + e0]);
        const float4 w4 = *reinterpret_cast<const float4*>(&w2[i * D + j0]);
        const float hv[4] = {h4.x, h4.y, h4.z, h4.w};
        const float wv[4] = {w4.x, w4.y, w4.z, w4.w};
        #pragma unroll
        for (int eq = 0; eq < 4; ++eq)
            #pragma unroll
            for (int jq = 0; jq < 4; ++jq)
                acc[eq][jq] = fmaf(hv[eq], wv[jq], acc[eq][jq]);
    }
    const float4 bb = *reinterpret_cast<const float4*>(&b2[j0]);
    const float bv[4] = {bb.x, bb.y, bb.z, bb.w};
    #pragma unroll
    for (int eq = 0; eq < 4; ++eq) {
        float4 r;
        r.x = acc[eq][0] + bv[0]; r.y = acc[eq][1] + bv[1];
        r.z = acc[eq][2] + bv[2]; r.w = acc[eq][3] + bv[3];
        *reinterpret_cast<float4*>(&out2[e0 + eq][j0]) = r;
    }
    __syncthreads();   // hn consumed; safe to overwrite after return
}

// second layer D->NHEAD (attention-bias MLP)
__device__ __forceinline__ void second_ea(
    int t, const float* hn, const float* __restrict__ w2,
    const float* __restrict__ b2, float ea2[EPB][NHEAD])
{
    const int e = t >> 3, hh = t & 7;
    float a = b2[hh];
    #pragma unroll 8
    for (int i = 0; i < D; ++i) a = fmaf(hn[i * HNS + e], w2[i * NHEAD + hh], a);
    ea2[e][hh] = a;
    __syncthreads();
}

// ---------------------------------------------------------------------------
// Fused per-edge kernel: 3 MLPs + gather + score + exp + denom atomics + vs
// ---------------------------------------------------------------------------
__global__ __launch_bounds__(128) void edge_kernel(
    const float* __restrict__ edge_feats,
    const int* __restrict__ bidx, const int* __restrict__ hidx, const int* __restrict__ tidx,
    const float* __restrict__ ea_w1, const float* __restrict__ ea_b1,
    const float* __restrict__ ea_g,  const float* __restrict__ ea_be,
    const float* __restrict__ ea_w2, const float* __restrict__ ea_b2,
    const float* __restrict__ ek_w1, const float* __restrict__ ek_b1,
    const float* __restrict__ ek_g,  const float* __restrict__ ek_be,
    const float* __restrict__ ek_w2, const float* __restrict__ ek_b2,
    const float* __restrict__ ev_w1, const float* __restrict__ ev_b1,
    const float* __restrict__ ev_g,  const float* __restrict__ ev_be,
    const float* __restrict__ ev_w2, const float* __restrict__ ev_b2,
    const float* __restrict__ k_ws, const float* __restrict__ q_ws, const float* __restrict__ v_ws,
    __hip_bfloat16* __restrict__ vs_ws, float* __restrict__ ex_ws, float* __restrict__ denom_ws)
{
    __shared__ float ef[EPB][8];
    __shared__ int   eidx[3][EPB];
    __shared__ float hn[D * HNS];
    __shared__ float part1[8][EPB], part2[8][EPB];
    __shared__ float mu_s[EPB], rs_s[EPB];
    __shared__ float ea2[EPB][NHEAD];
    __shared__ float ek2[EPB][D + 4];
    __shared__ float ev2[EPB][D + 4];

    const int t = threadIdx.x;
    const long e0g = (long)blockIdx.x * EPB;

    if (t < EPB * FE) ef[t / FE][t % FE] = edge_feats[e0g * FE + t];
    if (t < EPB) {
        eidx[0][t] = bidx[e0g + t];
        eidx[1][t] = hidx[e0g + t];
        eidx[2][t] = tidx[e0g + t];
    }
    __syncthreads();

    // --- ea MLP ---
    first_ln(t, ef, hn, ea_w1, ea_b1, ea_g, ea_be, part1, part2, mu_s, rs_s);
    second_ea(t, hn, ea_w2, ea_b2, ea2);
    // --- ek MLP ---
    first_ln(t, ef, hn, ek_w1, ek_b1, ek_g, ek_be, part1, part2, mu_s, rs_s);
    second_big(t, hn, ek_w2, ek_b2, ek2);
    // --- ev MLP ---
    first_ln(t, ef, hn, ev_w1, ev_b1, ev_g, ev_be, part1, part2, mu_s, rs_s);
    second_big(t, hn, ev_w2, ev_b2, ev2);

    // --- gather + score + exp + vs ---
    const int j = t, hh = j >> 4;
    for (int e = 0; e < EPB; ++e) {
        const int  bb = eidx[0][e];
        const long nh = (long)bb * LSEQ + eidx[1][e];
        const long nt = (long)bb * LSEQ + eidx[2][e];
        const float ksj = k_ws[nt * D + j] + ek2[e][j];
        const float qsj = q_ws[nh * D + j];
        const float vsj = v_ws[nt * D + j] + ev2[e][j];
        vs_ws[(e0g + e) * D + j] = __float2bfloat16(vsj);
        float p = ksj * qsj;
        p += __shfl_xor(p, 1);
        p += __shfl_xor(p, 2);
        p += __shfl_xor(p, 4);
        p += __shfl_xor(p, 8);
        if ((j & 15) == 0) {
            // segment-max skipped: |w| <~ 2, exp cannot overflow; ratio is
            // identical to max-subtracted form to fp32 accuracy.
            const float ex = __expf(p + ea2[e][hh]);
            ex_ws[(e0g + e) * NHEAD + hh] = ex;
            atomicAdd(&denom_ws[nh * NHEAD + hh], ex);
        }
    }
}

// ---------------------------------------------------------------------------
// Scatter: y[head_node] += att * vs   (one block per edge)
// ---------------------------------------------------------------------------
__global__ __launch_bounds__(128) void scatter_kernel(
    const int* __restrict__ bidx, const int* __restrict__ hidx,
    const float* __restrict__ ex_ws, const float* __restrict__ denom_ws,
    const __hip_bfloat16* __restrict__ vs_ws, float* __restrict__ y_ws)
{
    const long e = blockIdx.x;
    const int  j = threadIdx.x;
    const long nh = (long)bidx[e] * LSEQ + hidx[e];
    const int  hh = j >> 4;
    const float ex  = ex_ws[e * NHEAD + hh];
    const float den = denom_ws[nh * NHEAD + hh];
    const float att = ex / (den + EPS_SM);
    const float val = att * __bfloat162float(vs_ws[e * D + j]);
    atomicAdd(&y_ws[nh * D + j], val);
}

// ---------------------------------------------------------------------------
extern "C" void kernel_launch(void* const* d_in, const int* in_sizes, int n_in,
                              void* d_out, int out_size, void* d_ws, size_t ws_size,
                              hipStream_t stream)
{
    const float* key        = (const float*)d_in[0];
    const float* value      = (const float*)d_in[1];
    const float* query      = (const float*)d_in[2];
    const float* edge_feats = (const float*)d_in[3];
    const int*   bidx       = (const int*)d_in[5];
    const int*   hidx       = (const int*)d_in[6];
    const int*   tidx       = (const int*)d_in[7];
    const float* key_w   = (const float*)d_in[8];  const float* key_b   = (const float*)d_in[9];
    const float* query_w = (const float*)d_in[10]; const float* query_b = (const float*)d_in[11];
    const float* value_w = (const float*)d_in[12]; const float* value_b = (const float*)d_in[13];
    const float* proj_w  = (const float*)d_in[14]; const float* proj_b  = (const float*)d_in[15];

    const int N = in_sizes[0] / D;   // 16384 nodes
    const int E = in_sizes[5];       // 262144 edges

    char* ws = (char*)d_ws;
    float* k_ws     = (float*)ws;  ws += (size_t)N * D * 4;
    float* q_ws     = (float*)ws;  ws += (size_t)N * D * 4;
    float* v_ws     = (float*)ws;  ws += (size_t)N * D * 4;
    float* ex_ws    = (float*)ws;  ws += (size_t)E * NHEAD * 4;
    float* denom_ws = (float*)ws;  ws += (size_t)N * NHEAD * 4;
    float* y_ws     = (float*)ws;  ws += (size_t)N * D * 4;
    __hip_bfloat16* vs_ws = (__hip_bfloat16*)ws;  ws += (size_t)E * D * 2;

    hipMemsetAsync(denom_ws, 0, (size_t)N * NHEAD * 4, stream);
    hipMemsetAsync(y_ws,     0, (size_t)N * D * 4,     stream);

    gemm128<<<N / 8, 128, 0, stream>>>(key,   key_w,   key_b,   k_ws);
    gemm128<<<N / 8, 128, 0, stream>>>(query, query_w, query_b, q_ws);
    gemm128<<<N / 8, 128, 0, stream>>>(value, value_w, value_b, v_ws);

    edge_kernel<<<E / EPB, 128, 0, stream>>>(
        edge_feats, bidx, hidx, tidx,
        (const float*)d_in[16], (const float*)d_in[17], (const float*)d_in[18],
        (const float*)d_in[19], (const float*)d_in[20], (const float*)d_in[21],
        (const float*)d_in[22], (const float*)d_in[23], (const float*)d_in[24],
        (const float*)d_in[25], (const float*)d_in[26], (const float*)d_in[27],
        (const float*)d_in[28], (const float*)d_in[29], (const float*)d_in[30],
        (const float*)d_in[31], (const float*)d_in[32], (const float*)d_in[33],
        k_ws, q_ws, v_ws, vs_ws, ex_ws, denom_ws);

    scatter_kernel<<<E, 128, 0, stream>>>(bidx, hidx, ex_ws, denom_ws, vs_ws, y_ws);

    gemm128<<<N / 8, 128, 0, stream>>>(y_ws, proj_w, proj_b, (float*)d_out);
}

// Round 2
// 429.560 us; speedup vs baseline: 1.7829x; 1.7829x over previous
//
#include <hip/hip_runtime.h>
#include <hip/hip_bf16.h>

#define D      128
#define NHEAD  8
#define FE     5
#define LSEQ   4096
#define EPB    64          // edges per block in edge_kernel
#define EPS_LN 1e-5f
#define EPS_SM 1e-16f

typedef unsigned short ushort_t;
typedef __bf16 bf16x8 __attribute__((ext_vector_type(8)));
typedef float  f32x4  __attribute__((ext_vector_type(4)));

__device__ __forceinline__ ushort_t f2bf(float x) {
    __hip_bfloat16 b = __float2bfloat16(x);
    return __builtin_bit_cast(unsigned short, b);
}

union Pk8 { ushort_t u[8]; uint4 v; };

// ---------------------------------------------------------------------------
// Prep: swizzle the three second-layer weight matrices into bf16 MFMA
// B-fragment layout. Fragment f=(nt,s,l): 8 bf16 = w2[k=s*32+(l>>4)*8+j][n=nt*16+(l&15)]
// stored contiguously at dst[f*8].  ek/ev: 8 nt -> 2048 frags. ea: 1 nt (cols
// padded 8->16 with zeros) -> 256 frags.
// ---------------------------------------------------------------------------
__global__ __launch_bounds__(256) void prep_w2(
    const float* __restrict__ ekw2, const float* __restrict__ evw2,
    const float* __restrict__ eaw2,
    ushort_t* __restrict__ eksw, ushort_t* __restrict__ evsw,
    ushort_t* __restrict__ easw)
{
    const int g = blockIdx.x * 256 + threadIdx.x;
    const float* src; ushort_t* dst; int frag, ncols, nvalid;
    if (g < 2048)      { src = ekw2; dst = eksw; frag = g;        ncols = 128; nvalid = 128; }
    else if (g < 4096) { src = evw2; dst = evsw; frag = g - 2048; ncols = 128; nvalid = 128; }
    else if (g < 4352) { src = eaw2; dst = easw; frag = g - 4096; ncols = 8;   nvalid = 8; }
    else return;
    const int nt = frag >> 8;
    const int s  = (frag >> 6) & 3;
    const int l  = frag & 63;
    const int n  = nt * 16 + (l & 15);
    Pk8 pk;
    #pragma unroll
    for (int j = 0; j < 8; ++j) {
        const int k = s * 32 + (l >> 4) * 8 + j;
        const float v = (n < nvalid) ? src[k * ncols + n] : 0.f;
        pk.u[j] = f2bf(v);
    }
    *(uint4*)(dst + (size_t)frag * 8) = pk.v;
}

// ---------------------------------------------------------------------------
// Node projections: 3 GEMMs [N x 128] @ [128 x 128] fused in one launch.
// block = 128 threads (j), 8 rows per block.
// ---------------------------------------------------------------------------
__global__ __launch_bounds__(128) void qkv_gemm(
    const float* __restrict__ key, const float* __restrict__ value,
    const float* __restrict__ query,
    const float* __restrict__ key_w, const float* __restrict__ key_b,
    const float* __restrict__ value_w, const float* __restrict__ value_b,
    const float* __restrict__ query_w, const float* __restrict__ query_b,
    float* __restrict__ k_ws, float* __restrict__ v_ws, float* __restrict__ q_ws,
    int nb)   // blocks per matrix = N/8
{
    const int which = blockIdx.x / nb;
    const int r0    = (blockIdx.x % nb) * 8;
    const float* X = (which == 0) ? key   : (which == 1) ? value   : query;
    const float* W = (which == 0) ? key_w : (which == 1) ? value_w : query_w;
    const float* bias = (which == 0) ? key_b : (which == 1) ? value_b : query_b;
    float* Y = (which == 0) ? k_ws : (which == 1) ? v_ws : q_ws;

    __shared__ float xs[8][D];
    const int j = threadIdx.x;
    #pragma unroll
    for (int r = 0; r < 8; ++r) xs[r][j] = X[(size_t)(r0 + r) * D + j];
    __syncthreads();
    float acc[8];
    const float b = bias[j];
    #pragma unroll
    for (int r = 0; r < 8; ++r) acc[r] = b;
    #pragma unroll 4
    for (int i = 0; i < D; ++i) {
        const float w = W[i * D + j];
        #pragma unroll
        for (int r = 0; r < 8; ++r) acc[r] = fmaf(xs[r][i], w, acc[r]);
    }
    #pragma unroll
    for (int r = 0; r < 8; ++r) Y[(size_t)(r0 + r) * D + j] = acc[r];
}

// ---------------------------------------------------------------------------
// Final projection with fused normalization: Y = (num/(den+eps)) @ W + b
// ---------------------------------------------------------------------------
__global__ __launch_bounds__(128) void out_gemm(
    const float* __restrict__ num, const float* __restrict__ den,
    const float* __restrict__ W, const float* __restrict__ bias,
    float* __restrict__ Y)
{
    __shared__ float xs[8][D];
    const int j  = threadIdx.x;
    const int r0 = blockIdx.x * 8;
    #pragma unroll
    for (int r = 0; r < 8; ++r) {
        const float d = den[(size_t)(r0 + r) * NHEAD + (j >> 4)];
        xs[r][j] = num[(size_t)(r0 + r) * D + j] / (d + EPS_SM);
    }
    __syncthreads();
    float acc[8];
    const float b = bias[j];
    #pragma unroll
    for (int r = 0; r < 8; ++r) acc[r] = b;
    #pragma unroll 4
    for (int i = 0; i < D; ++i) {
        const float w = W[i * D + j];
        #pragma unroll
        for (int r = 0; r < 8; ++r) acc[r] = fmaf(xs[r][i], w, acc[r]);
    }
    #pragma unroll
    for (int r = 0; r < 8; ++r) Y[(size_t)(r0 + r) * D + j] = acc[r];
}

// ---------------------------------------------------------------------------
// Fused edge kernel, MFMA second layers.
// Block = 256 threads (4 waves), 64 edges. Wave w owns edges [w*16, w*16+16).
// hn LDS is stored directly in A-fragment order: chunk (mt*4+s)*64 + l holds
// lane l's 8 bf16 A-fragment for m-tile mt, k-step s (zero-conflict, wave-private).
// ---------------------------------------------------------------------------
__global__ __launch_bounds__(256) void edge_kernel(
    const float* __restrict__ edge_feats,
    const int* __restrict__ bidx, const int* __restrict__ hidx, const int* __restrict__ tidx,
    const float* __restrict__ ea_w1, const float* __restrict__ ea_b1,
    const float* __restrict__ ea_g,  const float* __restrict__ ea_be, const float* __restrict__ ea_b2,
    const float* __restrict__ ek_w1, const float* __restrict__ ek_b1,
    const float* __restrict__ ek_g,  const float* __restrict__ ek_be, const float* __restrict__ ek_b2,
    const float* __restrict__ ev_w1, const float* __restrict__ ev_b1,
    const float* __restrict__ ev_g,  const float* __restrict__ ev_be, const float* __restrict__ ev_b2,
    const ushort_t* __restrict__ easw, const ushort_t* __restrict__ eksw, const ushort_t* __restrict__ evsw,
    const float* __restrict__ k_ws, const float* __restrict__ q_ws, const float* __restrict__ v_ws,
    float* __restrict__ denom_ws, float* __restrict__ ynum_ws)
{
    __shared__ float pw1[3][FE * D];          // 7680 B
    __shared__ float pb1[3][D], pg[3][D], pbe[3][D];
    __shared__ float pb2k[D], pb2v[D], pb2a[NHEAD];
    __shared__ float ef_s[EPB][FE];
    __shared__ int   eh_s[EPB], et_s[EPB];
    __shared__ __align__(16) ushort_t hn_sw[4 * 4 * 64 * 8];   // 16 KB
    __shared__ float sc_s[EPB][NHEAD];        // ea2 then ex (wave-private rows)

    const int t   = threadIdx.x;
    const int e0g = blockIdx.x * EPB;

    // ---- preload parameters / edge data ----
    for (int i = t; i < FE * D; i += 256) { pw1[0][i] = ea_w1[i]; pw1[1][i] = ek_w1[i]; pw1[2][i] = ev_w1[i]; }
    if (t < D) {
        pb1[0][t] = ea_b1[t]; pb1[1][t] = ek_b1[t]; pb1[2][t] = ev_b1[t];
        pg [0][t] = ea_g [t]; pg [1][t] = ek_g [t]; pg [2][t] = ev_g [t];
        pbe[0][t] = ea_be[t]; pbe[1][t] = ek_be[t]; pbe[2][t] = ev_be[t];
        pb2k[t] = ek_b2[t];   pb2v[t] = ev_b2[t];
        if (t < NHEAD) pb2a[t] = ea_b2[t];
    }
    for (int i = t; i < EPB * FE; i += 256) ((float*)ef_s)[i] = edge_feats[(size_t)e0g * FE + i];
    if (t < EPB) {
        const int bb = bidx[e0g + t];
        eh_s[t] = bb * LSEQ + hidx[e0g + t];
        et_s[t] = bb * LSEQ + tidx[e0g + t];
    }
    __syncthreads();

    const int e    = t >> 2;        // local edge for first layer (0..63)
    const int dg   = t & 3;         // dim group: dims [dg*32, dg*32+32) ; == k-step s
    const int mt   = t >> 6;        // wave id == m-tile
    const int l    = t & 63;        // lane
    const int e0   = mt * 16;
    const int row0 = (l >> 4) * 4;
    const int colb = l & 15;

    int tn[4], hnn[4];
    #pragma unroll
    for (int r = 0; r < 4; ++r) { tn[r] = et_s[e0 + row0 + r]; hnn[r] = eh_s[e0 + row0 + r]; }

    float efr[FE];
    #pragma unroll
    for (int f = 0; f < FE; ++f) efr[f] = ef_s[e][f];
    const int c4 = dg * 8;          // float4 index base of this thread's 32 dims

    // ---- first layer + LN -> bf16 A-fragments in LDS (wave-private) ----
    auto first_layer = [&](int m) {
        const float4* w1v = (const float4*)&pw1[m][0];
        const float4* b1v = (const float4*)&pb1[m][0];
        const float4* gv  = (const float4*)&pg[m][0];
        const float4* bev = (const float4*)&pbe[m][0];
        float4 hv[8];
        float s1 = 0.f, s2 = 0.f;
        #pragma unroll
        for (int c = 0; c < 8; ++c) {
            float4 a = b1v[c4 + c];
            #pragma unroll
            for (int f = 0; f < FE; ++f) {
                const float s = efr[f];
                const float4 w = w1v[f * 32 + c4 + c];
                a.x = fmaf(s, w.x, a.x); a.y = fmaf(s, w.y, a.y);
                a.z = fmaf(s, w.z, a.z); a.w = fmaf(s, w.w, a.w);
            }
            a.x = fmaxf(a.x, 0.f); a.y = fmaxf(a.y, 0.f);
            a.z = fmaxf(a.z, 0.f); a.w = fmaxf(a.w, 0.f);
            hv[c] = a;
            s1 += a.x + a.y + a.z + a.w;
            s2 += a.x * a.x + a.y * a.y + a.z * a.z + a.w * a.w;
        }
        s1 += __shfl_xor(s1, 1); s1 += __shfl_xor(s1, 2);
        s2 += __shfl_xor(s2, 1); s2 += __shfl_xor(s2, 2);
        const float mu = s1 * (1.f / 128.f);
        const float rs = rsqrtf(s2 * (1.f / 128.f) - mu * mu + EPS_LN);
        #pragma unroll
        for (int qq = 0; qq < 4; ++qq) {
            const float4 x0 = hv[qq * 2 + 0], x1 = hv[qq * 2 + 1];
            const float4 g0 = gv[c4 + qq * 2 + 0],  g1 = gv[c4 + qq * 2 + 1];
            const float4 b0 = bev[c4 + qq * 2 + 0], b1 = bev[c4 + qq * 2 + 1];
            Pk8 pk;
            pk.u[0] = f2bf(fmaf((x0.x - mu) * rs, g0.x, b0.x));
            pk.u[1] = f2bf(fmaf((x0.y - mu) * rs, g0.y, b0.y));
            pk.u[2] = f2bf(fmaf((x0.z - mu) * rs, g0.z, b0.z));
            pk.u[3] = f2bf(fmaf((x0.w - mu) * rs, g0.w, b0.w));
            pk.u[4] = f2bf(fmaf((x1.x - mu) * rs, g1.x, b1.x));
            pk.u[5] = f2bf(fmaf((x1.y - mu) * rs, g1.y, b1.y));
            pk.u[6] = f2bf(fmaf((x1.z - mu) * rs, g1.z, b1.z));
            pk.u[7] = f2bf(fmaf((x1.w - mu) * rs, g1.w, b1.w));
            const int chunk = ((e >> 4) * 4 + dg) * 64 + (e & 15) + 16 * qq;
            *(uint4*)&hn_sw[chunk * 8] = pk.v;
        }
    };

    auto load_afr = [&](bf16x8 afr[4]) {
        #pragma unroll
        for (int s = 0; s < 4; ++s)
            afr[s] = *(const bf16x8*)&hn_sw[((mt * 4 + s) * 64 + l) * 8];
    };

    // ================= MLP 0: ea (attention bias, N=8 padded to 16) =========
    first_layer(0);
    __syncthreads();
    {
        bf16x8 afr[4]; load_afr(afr);
        f32x4 acc = {0.f, 0.f, 0.f, 0.f};
        #pragma unroll
        for (int s = 0; s < 4; ++s) {
            const bf16x8 bfr = *(const bf16x8*)(easw + (size_t)(s * 64 + l) * 8);
            acc = __builtin_amdgcn_mfma_f32_16x16x32_bf16(afr[s], bfr, acc, 0, 0, 0);
        }
        if (colb < NHEAD) {
            #pragma unroll
            for (int r = 0; r < 4; ++r)
                sc_s[e0 + row0 + r][colb] = acc[r] + pb2a[colb];
        }
    }
    __syncthreads();

    // ================= MLP 1: ek -> scores -> exp -> denom ==================
    first_layer(1);
    __syncthreads();
    {
        bf16x8 afr[4]; load_afr(afr);
        #pragma unroll 1
        for (int nt = 0; nt < 8; ++nt) {
            f32x4 acc = {0.f, 0.f, 0.f, 0.f};
            #pragma unroll
            for (int s = 0; s < 4; ++s) {
                const bf16x8 bfr = *(const bf16x8*)(eksw + (size_t)((nt * 4 + s) * 64 + l) * 8);
                acc = __builtin_amdgcn_mfma_f32_16x16x32_bf16(afr[s], bfr, acc, 0, 0, 0);
            }
            const int col = nt * 16 + colb;
            const float b2 = pb2k[col];
            float pr[4];
            #pragma unroll
            for (int r = 0; r < 4; ++r) {
                const float ks = acc[r] + b2 + k_ws[(size_t)tn[r] * D + col];
                const float qs = q_ws[(size_t)hnn[r] * D + col];
                pr[r] = ks * qs;
            }
            #pragma unroll
            for (int m = 1; m < 16; m <<= 1) {
                #pragma unroll
                for (int r = 0; r < 4; ++r) pr[r] += __shfl_xor(pr[r], m);
            }
            #pragma unroll
            for (int r = 0; r < 4; ++r) {
                // segment-max skipped: |score| small, exp cannot overflow.
                const float ex = __expf(pr[r] + sc_s[e0 + row0 + r][nt]);
                if (colb == 0) {
                    sc_s[e0 + row0 + r][nt] = ex;
                    atomicAdd(&denom_ws[(size_t)hnn[r] * NHEAD + nt], ex);
                }
            }
        }
    }
    __syncthreads();

    // ================= MLP 2: ev -> weighted scatter (unnormalized) =========
    first_layer(2);
    __syncthreads();
    {
        bf16x8 afr[4]; load_afr(afr);
        #pragma unroll 1
        for (int nt = 0; nt < 8; ++nt) {
            f32x4 acc = {0.f, 0.f, 0.f, 0.f};
            #pragma unroll
            for (int s = 0; s < 4; ++s) {
                const bf16x8 bfr = *(const bf16x8*)(evsw + (size_t)((nt * 4 + s) * 64 + l) * 8);
                acc = __builtin_amdgcn_mfma_f32_16x16x32_bf16(afr[s], bfr, acc, 0, 0, 0);
            }
            const int col = nt * 16 + colb;
            const float b2 = pb2v[col];
            #pragma unroll
            for (int r = 0; r < 4; ++r) {
                const float vs = acc[r] + b2 + v_ws[(size_t)tn[r] * D + col];
                const float val = sc_s[e0 + row0 + r][nt] * vs;
                atomicAdd(&ynum_ws[(size_t)hnn[r] * D + col], val);
            }
        }
    }
}

// ---------------------------------------------------------------------------
extern "C" void kernel_launch(void* const* d_in, const int* in_sizes, int n_in,
                              void* d_out, int out_size, void* d_ws, size_t ws_size,
                              hipStream_t stream)
{
    const float* key        = (const float*)d_in[0];
    const float* value      = (const float*)d_in[1];
    const float* query      = (const float*)d_in[2];
    const float* edge_feats = (const float*)d_in[3];
    const int*   bidx       = (const int*)d_in[5];
    const int*   hidx       = (const int*)d_in[6];
    const int*   tidx       = (const int*)d_in[7];
    const float* key_w   = (const float*)d_in[8];  const float* key_b   = (const float*)d_in[9];
    const float* query_w = (const float*)d_in[10]; const float* query_b = (const float*)d_in[11];
    const float* value_w = (const float*)d_in[12]; const float* value_b = (const float*)d_in[13];
    const float* proj_w  = (const float*)d_in[14]; const float* proj_b  = (const float*)d_in[15];

    const int N = in_sizes[0] / D;   // 16384 nodes
    const int E = in_sizes[5];       // 262144 edges

    char* ws = (char*)d_ws;
    float* k_ws     = (float*)ws;  ws += (size_t)N * D * 4;
    float* q_ws     = (float*)ws;  ws += (size_t)N * D * 4;
    float* v_ws     = (float*)ws;  ws += (size_t)N * D * 4;
    float* denom_ws = (float*)ws;  ws += (size_t)N * NHEAD * 4;
    float* ynum_ws  = (float*)ws;  ws += (size_t)N * D * 4;
    ushort_t* eksw  = (ushort_t*)ws; ws += (size_t)2048 * 8 * 2;
    ushort_t* evsw  = (ushort_t*)ws; ws += (size_t)2048 * 8 * 2;
    ushort_t* easw  = (ushort_t*)ws; ws += (size_t)256 * 8 * 2;

    hipMemsetAsync(denom_ws, 0, (size_t)N * NHEAD * 4, stream);
    hipMemsetAsync(ynum_ws,  0, (size_t)N * D * 4,     stream);

    prep_w2<<<17, 256, 0, stream>>>((const float*)d_in[26], (const float*)d_in[32],
                                    (const float*)d_in[20], eksw, evsw, easw);

    qkv_gemm<<<3 * (N / 8), 128, 0, stream>>>(key, value, query,
                                              key_w, key_b, value_w, value_b, query_w, query_b,
                                              k_ws, v_ws, q_ws, N / 8);

    edge_kernel<<<E / EPB, 256, 0, stream>>>(
        edge_feats, bidx, hidx, tidx,
        (const float*)d_in[16], (const float*)d_in[17], (const float*)d_in[18],
        (const float*)d_in[19], (const float*)d_in[21],
        (const float*)d_in[22], (const float*)d_in[23], (const float*)d_in[24],
        (const float*)d_in[25], (const float*)d_in[27],
        (const float*)d_in[28], (const float*)d_in[29], (const float*)d_in[30],
        (const float*)d_in[31], (const float*)d_in[33],
        easw, eksw, evsw,
        k_ws, q_ws, v_ws, denom_ws, ynum_ws);

    out_gemm<<<N / 8, 128, 0, stream>>>(ynum_ws, denom_ws, proj_w, proj_b, (float*)d_out);
}

// Round 3
// 426.526 us; speedup vs baseline: 1.7955x; 1.0071x over previous
//
#include <hip/hip_runtime.h>
#include <hip/hip_bf16.h>

#define D      128
#define NHEAD  8
#define FE     5
#define LSEQ   4096
#define EPB    64          // edges per block in edge_kernel
#define EPS_LN 1e-5f
#define EPS_SM 1e-16f

typedef unsigned short ushort_t;
typedef __bf16 bf16x8 __attribute__((ext_vector_type(8)));
typedef float  f32x4  __attribute__((ext_vector_type(4)));

__device__ __forceinline__ ushort_t f2bf(float x) {
    __hip_bfloat16 b = __float2bfloat16(x);
    return __builtin_bit_cast(unsigned short, b);
}

union Pk8 { ushort_t u[8]; uint4 v; };

// ---------------------------------------------------------------------------
// Prep: swizzle second-layer weights into bf16 MFMA B-fragment layout.
// Fragment f=(nt,s,l): 8 bf16 = w2[k=s*32+(l>>4)*8+j][n=nt*16+(l&15)] at dst[f*8].
// ---------------------------------------------------------------------------
__global__ __launch_bounds__(256) void prep_w2(
    const float* __restrict__ ekw2, const float* __restrict__ evw2,
    const float* __restrict__ eaw2,
    ushort_t* __restrict__ eksw, ushort_t* __restrict__ evsw,
    ushort_t* __restrict__ easw)
{
    const int g = blockIdx.x * 256 + threadIdx.x;
    const float* src; ushort_t* dst; int frag, ncols, nvalid;
    if (g < 2048)      { src = ekw2; dst = eksw; frag = g;        ncols = 128; nvalid = 128; }
    else if (g < 4096) { src = evw2; dst = evsw; frag = g - 2048; ncols = 128; nvalid = 128; }
    else if (g < 4352) { src = eaw2; dst = easw; frag = g - 4096; ncols = 8;   nvalid = 8; }
    else return;
    const int nt = frag >> 8;
    const int s  = (frag >> 6) & 3;
    const int l  = frag & 63;
    const int n  = nt * 16 + (l & 15);
    Pk8 pk;
    #pragma unroll
    for (int j = 0; j < 8; ++j) {
        const int k = s * 32 + (l >> 4) * 8 + j;
        const float v = (n < nvalid) ? src[k * ncols + n] : 0.f;
        pk.u[j] = f2bf(v);
    }
    *(uint4*)(dst + (size_t)frag * 8) = pk.v;
}

// ---------------------------------------------------------------------------
// Node projections: 3 GEMMs [N x 128] @ [128 x 128], 16 rows/block,
// transposed padded LDS (broadcast b128 reads). Also zeroes denom+ynum.
// ---------------------------------------------------------------------------
__global__ __launch_bounds__(128) void qkv_gemm(
    const float* __restrict__ key, const float* __restrict__ value,
    const float* __restrict__ query,
    const float* __restrict__ key_w, const float* __restrict__ key_b,
    const float* __restrict__ value_w, const float* __restrict__ value_b,
    const float* __restrict__ query_w, const float* __restrict__ query_b,
    float* __restrict__ k_ws, float* __restrict__ v_ws, float* __restrict__ q_ws,
    float4* __restrict__ zero_base, int nzero4,   // denom+ynum zero span
    int nb)   // blocks per matrix = N/16
{
    // ---- fused zero of denom_ws + ynum_ws (atomic destinations) ----
    for (int idx = blockIdx.x * 128 + threadIdx.x; idx < nzero4; idx += gridDim.x * 128)
        zero_base[idx] = float4{0.f, 0.f, 0.f, 0.f};

    const int which = blockIdx.x / nb;
    const int r0    = (blockIdx.x % nb) * 16;
    const float* X = (which == 0) ? key   : (which == 1) ? value   : query;
    const float* W = (which == 0) ? key_w : (which == 1) ? value_w : query_w;
    const float* bias = (which == 0) ? key_b : (which == 1) ? value_b : query_b;
    float* Y = (which == 0) ? k_ws : (which == 1) ? v_ws : q_ws;

    __shared__ float xs[D][20];       // transposed, padded (8-way floor on write)
    const int j = threadIdx.x;
    {
        float tmp[16];
        #pragma unroll
        for (int r = 0; r < 16; ++r) tmp[r] = X[(size_t)(r0 + r) * D + j];
        #pragma unroll
        for (int c = 0; c < 4; ++c)
            *(float4*)&xs[j][c * 4] = float4{tmp[c*4], tmp[c*4+1], tmp[c*4+2], tmp[c*4+3]};
    }
    __syncthreads();
    float acc[16];
    const float b = bias[j];
    #pragma unroll
    for (int r = 0; r < 16; ++r) acc[r] = b;
    #pragma unroll 4
    for (int i = 0; i < D; ++i) {
        const float w = W[i * D + j];
        #pragma unroll
        for (int c = 0; c < 4; ++c) {
            const float4 x4 = *(const float4*)&xs[i][c * 4];
            acc[c*4+0] = fmaf(x4.x, w, acc[c*4+0]);
            acc[c*4+1] = fmaf(x4.y, w, acc[c*4+1]);
            acc[c*4+2] = fmaf(x4.z, w, acc[c*4+2]);
            acc[c*4+3] = fmaf(x4.w, w, acc[c*4+3]);
        }
    }
    #pragma unroll
    for (int r = 0; r < 16; ++r) Y[(size_t)(r0 + r) * D + j] = acc[r];
}

// ---------------------------------------------------------------------------
// Final projection with fused normalization: Y = (num/(den+eps)) @ W + b
// ---------------------------------------------------------------------------
__global__ __launch_bounds__(128) void out_gemm(
    const float* __restrict__ num, const float* __restrict__ den,
    const float* __restrict__ W, const float* __restrict__ bias,
    float* __restrict__ Y)
{
    __shared__ float xs[D][20];
    const int j  = threadIdx.x;
    const int r0 = blockIdx.x * 16;
    {
        float tmp[16];
        #pragma unroll
        for (int r = 0; r < 16; ++r) {
            const float d = den[(size_t)(r0 + r) * NHEAD + (j >> 4)];
            tmp[r] = num[(size_t)(r0 + r) * D + j] / (d + EPS_SM);
        }
        #pragma unroll
        for (int c = 0; c < 4; ++c)
            *(float4*)&xs[j][c * 4] = float4{tmp[c*4], tmp[c*4+1], tmp[c*4+2], tmp[c*4+3]};
    }
    __syncthreads();
    float acc[16];
    const float b = bias[j];
    #pragma unroll
    for (int r = 0; r < 16; ++r) acc[r] = b;
    #pragma unroll 4
    for (int i = 0; i < D; ++i) {
        const float w = W[i * D + j];
        #pragma unroll
        for (int c = 0; c < 4; ++c) {
            const float4 x4 = *(const float4*)&xs[i][c * 4];
            acc[c*4+0] = fmaf(x4.x, w, acc[c*4+0]);
            acc[c*4+1] = fmaf(x4.y, w, acc[c*4+1]);
            acc[c*4+2] = fmaf(x4.z, w, acc[c*4+2]);
            acc[c*4+3] = fmaf(x4.w, w, acc[c*4+3]);
        }
    }
    #pragma unroll
    for (int r = 0; r < 16; ++r) Y[(size_t)(r0 + r) * D + j] = acc[r];
}

// ---------------------------------------------------------------------------
// Fused edge kernel, MFMA second layers, prefetched gathers.
// Block = 256 threads (4 waves), 64 edges. Wave w owns edges [w*16, w*16+16).
// ---------------------------------------------------------------------------
__global__ __launch_bounds__(256, 3) void edge_kernel(
    const float* __restrict__ edge_feats,
    const int* __restrict__ bidx, const int* __restrict__ hidx, const int* __restrict__ tidx,
    const float* __restrict__ ea_w1, const float* __restrict__ ea_b1,
    const float* __restrict__ ea_g,  const float* __restrict__ ea_be, const float* __restrict__ ea_b2,
    const float* __restrict__ ek_w1, const float* __restrict__ ek_b1,
    const float* __restrict__ ek_g,  const float* __restrict__ ek_be, const float* __restrict__ ek_b2,
    const float* __restrict__ ev_w1, const float* __restrict__ ev_b1,
    const float* __restrict__ ev_g,  const float* __restrict__ ev_be, const float* __restrict__ ev_b2,
    const ushort_t* __restrict__ easw, const ushort_t* __restrict__ eksw, const ushort_t* __restrict__ evsw,
    const float* __restrict__ k_ws, const float* __restrict__ q_ws, const float* __restrict__ v_ws,
    float* __restrict__ denom_ws, float* __restrict__ ynum_ws)
{
    __shared__ float pw1[3][FE * D];
    __shared__ float pb1[3][D], pg[3][D], pbe[3][D];
    __shared__ float pb2k[D], pb2v[D], pb2a[NHEAD];
    __shared__ float ef_s[EPB][FE];
    __shared__ int   eh_s[EPB], et_s[EPB];
    __shared__ __align__(16) ushort_t hn_sw[4 * 4 * 64 * 8];   // 16 KB
    __shared__ float sc_s[EPB][NHEAD];        // ea2 then ex (wave-private rows)

    const int t   = threadIdx.x;
    const int e0g = blockIdx.x * EPB;

    // ---- preload parameters / edge data ----
    for (int i = t; i < FE * D; i += 256) { pw1[0][i] = ea_w1[i]; pw1[1][i] = ek_w1[i]; pw1[2][i] = ev_w1[i]; }
    if (t < D) {
        pb1[0][t] = ea_b1[t]; pb1[1][t] = ek_b1[t]; pb1[2][t] = ev_b1[t];
        pg [0][t] = ea_g [t]; pg [1][t] = ek_g [t]; pg [2][t] = ev_g [t];
        pbe[0][t] = ea_be[t]; pbe[1][t] = ek_be[t]; pbe[2][t] = ev_be[t];
        pb2k[t] = ek_b2[t];   pb2v[t] = ev_b2[t];
        if (t < NHEAD) pb2a[t] = ea_b2[t];
    }
    for (int i = t; i < EPB * FE; i += 256) ((float*)ef_s)[i] = edge_feats[(size_t)e0g * FE + i];
    if (t < EPB) {
        const int bb = bidx[e0g + t];
        eh_s[t] = bb * LSEQ + hidx[e0g + t];
        et_s[t] = bb * LSEQ + tidx[e0g + t];
    }
    __syncthreads();

    const int e    = t >> 2;        // local edge for first layer (0..63)
    const int dg   = t & 3;         // dim group: dims [dg*32, dg*32+32)
    const int mt   = t >> 6;        // wave id == m-tile
    const int l    = t & 63;        // lane
    const int e0   = mt * 16;
    const int row0 = (l >> 4) * 4;
    const int colb = l & 15;

    int tn[4], hnn[4];
    #pragma unroll
    for (int r = 0; r < 4; ++r) { tn[r] = et_s[e0 + row0 + r]; hnn[r] = eh_s[e0 + row0 + r]; }

    float efr[FE];
    #pragma unroll
    for (int f = 0; f < FE; ++f) efr[f] = ef_s[e][f];
    const int c4 = dg * 8;

    auto first_layer = [&](int m) {
        const float4* w1v = (const float4*)&pw1[m][0];
        const float4* b1v = (const float4*)&pb1[m][0];
        const float4* gv  = (const float4*)&pg[m][0];
        const float4* bev = (const float4*)&pbe[m][0];
        float4 hv[8];
        float s1 = 0.f, s2 = 0.f;
        #pragma unroll
        for (int c = 0; c < 8; ++c) {
            float4 a = b1v[c4 + c];
            #pragma unroll
            for (int f = 0; f < FE; ++f) {
                const float s = efr[f];
                const float4 w = w1v[f * 32 + c4 + c];
                a.x = fmaf(s, w.x, a.x); a.y = fmaf(s, w.y, a.y);
                a.z = fmaf(s, w.z, a.z); a.w = fmaf(s, w.w, a.w);
            }
            a.x = fmaxf(a.x, 0.f); a.y = fmaxf(a.y, 0.f);
            a.z = fmaxf(a.z, 0.f); a.w = fmaxf(a.w, 0.f);
            hv[c] = a;
            s1 += a.x + a.y + a.z + a.w;
            s2 += a.x * a.x + a.y * a.y + a.z * a.z + a.w * a.w;
        }
        s1 += __shfl_xor(s1, 1); s1 += __shfl_xor(s1, 2);
        s2 += __shfl_xor(s2, 1); s2 += __shfl_xor(s2, 2);
        const float mu = s1 * (1.f / 128.f);
        const float rs = rsqrtf(s2 * (1.f / 128.f) - mu * mu + EPS_LN);
        #pragma unroll
        for (int qq = 0; qq < 4; ++qq) {
            const float4 x0 = hv[qq * 2 + 0], x1 = hv[qq * 2 + 1];
            const float4 g0 = gv[c4 + qq * 2 + 0],  g1 = gv[c4 + qq * 2 + 1];
            const float4 b0 = bev[c4 + qq * 2 + 0], b1 = bev[c4 + qq * 2 + 1];
            Pk8 pk;
            pk.u[0] = f2bf(fmaf((x0.x - mu) * rs, g0.x, b0.x));
            pk.u[1] = f2bf(fmaf((x0.y - mu) * rs, g0.y, b0.y));
            pk.u[2] = f2bf(fmaf((x0.z - mu) * rs, g0.z, b0.z));
            pk.u[3] = f2bf(fmaf((x0.w - mu) * rs, g0.w, b0.w));
            pk.u[4] = f2bf(fmaf((x1.x - mu) * rs, g1.x, b1.x));
            pk.u[5] = f2bf(fmaf((x1.y - mu) * rs, g1.y, b1.y));
            pk.u[6] = f2bf(fmaf((x1.z - mu) * rs, g1.z, b1.z));
            pk.u[7] = f2bf(fmaf((x1.w - mu) * rs, g1.w, b1.w));
            const int chunk = ((e >> 4) * 4 + dg) * 64 + (e & 15) + 16 * qq;
            *(uint4*)&hn_sw[chunk * 8] = pk.v;
        }
    };

    auto load_afr = [&](bf16x8 afr[4]) {
        #pragma unroll
        for (int s = 0; s < 4; ++s)
            afr[s] = *(const bf16x8*)&hn_sw[((mt * 4 + s) * 64 + l) * 8];
    };

    // ================= MLP 0: ea (attention bias, N=8 padded to 16) =========
    first_layer(0);
    __syncthreads();
    {
        bf16x8 afr[4]; load_afr(afr);
        f32x4 acc = {0.f, 0.f, 0.f, 0.f};
        #pragma unroll
        for (int s = 0; s < 4; ++s) {
            const bf16x8 bfr = *(const bf16x8*)(easw + (size_t)(s * 64 + l) * 8);
            acc = __builtin_amdgcn_mfma_f32_16x16x32_bf16(afr[s], bfr, acc, 0, 0, 0);
        }
        if (colb < NHEAD) {
            #pragma unroll
            for (int r = 0; r < 4; ++r)
                sc_s[e0 + row0 + r][colb] = acc[r] + pb2a[colb];
        }
    }
    __syncthreads();

    // ================= MLP 1: ek -> scores -> exp -> denom ==================
    first_layer(1);
    __syncthreads();
    float vv[8][4];    // v gathers, prefetched at end of ek phase
    {
        // prefetch ALL k/q gathers up-front (one latency exposure)
        float kv[8][4], qv[8][4];
        #pragma unroll
        for (int nt = 0; nt < 8; ++nt) {
            const int col = nt * 16 + colb;
            #pragma unroll
            for (int r = 0; r < 4; ++r) {
                kv[nt][r] = k_ws[(size_t)tn[r] * D + col];
                qv[nt][r] = q_ws[(size_t)hnn[r] * D + col];
            }
        }
        bf16x8 afr[4]; load_afr(afr);
        #pragma unroll
        for (int nt = 0; nt < 8; ++nt) {
            f32x4 acc = {0.f, 0.f, 0.f, 0.f};
            #pragma unroll
            for (int s = 0; s < 4; ++s) {
                const bf16x8 bfr = *(const bf16x8*)(eksw + (size_t)((nt * 4 + s) * 64 + l) * 8);
                acc = __builtin_amdgcn_mfma_f32_16x16x32_bf16(afr[s], bfr, acc, 0, 0, 0);
            }
            const float b2 = pb2k[nt * 16 + colb];
            float pr[4];
            #pragma unroll
            for (int r = 0; r < 4; ++r) pr[r] = (acc[r] + b2 + kv[nt][r]) * qv[nt][r];
            #pragma unroll
            for (int m = 1; m < 16; m <<= 1) {
                #pragma unroll
                for (int r = 0; r < 4; ++r) pr[r] += __shfl_xor(pr[r], m);
            }
            #pragma unroll
            for (int r = 0; r < 4; ++r) {
                // segment-max skipped: |score| small, exp cannot overflow.
                const float ex = __expf(pr[r] + sc_s[e0 + row0 + r][nt]);
                if (colb == 0) {
                    sc_s[e0 + row0 + r][nt] = ex;
                    atomicAdd(&denom_ws[(size_t)hnn[r] * NHEAD + nt], ex);
                }
            }
        }
        // prefetch v gathers now — they fly during first_layer(2)
        #pragma unroll
        for (int nt = 0; nt < 8; ++nt) {
            const int col = nt * 16 + colb;
            #pragma unroll
            for (int r = 0; r < 4; ++r) vv[nt][r] = v_ws[(size_t)tn[r] * D + col];
        }
    }
    __syncthreads();

    // ================= MLP 2: ev -> weighted scatter (unnormalized) =========
    first_layer(2);
    __syncthreads();
    {
        bf16x8 afr[4]; load_afr(afr);
        #pragma unroll
        for (int nt = 0; nt < 8; ++nt) {
            f32x4 acc = {0.f, 0.f, 0.f, 0.f};
            #pragma unroll
            for (int s = 0; s < 4; ++s) {
                const bf16x8 bfr = *(const bf16x8*)(evsw + (size_t)((nt * 4 + s) * 64 + l) * 8);
                acc = __builtin_amdgcn_mfma_f32_16x16x32_bf16(afr[s], bfr, acc, 0, 0, 0);
            }
            const int col = nt * 16 + colb;
            const float b2 = pb2v[col];
            #pragma unroll
            for (int r = 0; r < 4; ++r) {
                const float vs = acc[r] + b2 + vv[nt][r];
                const float val = sc_s[e0 + row0 + r][nt] * vs;
                atomicAdd(&ynum_ws[(size_t)hnn[r] * D + col], val);
            }
        }
    }
}

// ---------------------------------------------------------------------------
extern "C" void kernel_launch(void* const* d_in, const int* in_sizes, int n_in,
                              void* d_out, int out_size, void* d_ws, size_t ws_size,
                              hipStream_t stream)
{
    const float* key        = (const float*)d_in[0];
    const float* value      = (const float*)d_in[1];
    const float* query      = (const float*)d_in[2];
    const float* edge_feats = (const float*)d_in[3];
    const int*   bidx       = (const int*)d_in[5];
    const int*   hidx       = (const int*)d_in[6];
    const int*   tidx       = (const int*)d_in[7];
    const float* key_w   = (const float*)d_in[8];  const float* key_b   = (const float*)d_in[9];
    const float* query_w = (const float*)d_in[10]; const float* query_b = (const float*)d_in[11];
    const float* value_w = (const float*)d_in[12]; const float* value_b = (const float*)d_in[13];
    const float* proj_w  = (const float*)d_in[14]; const float* proj_b  = (const float*)d_in[15];

    const int N = in_sizes[0] / D;   // 16384 nodes
    const int E = in_sizes[5];       // 262144 edges

    char* ws = (char*)d_ws;
    float* k_ws     = (float*)ws;  ws += (size_t)N * D * 4;
    float* q_ws     = (float*)ws;  ws += (size_t)N * D * 4;
    float* v_ws     = (float*)ws;  ws += (size_t)N * D * 4;
    float* denom_ws = (float*)ws;  ws += (size_t)N * NHEAD * 4;
    float* ynum_ws  = (float*)ws;  ws += (size_t)N * D * 4;     // contiguous after denom
    ushort_t* eksw  = (ushort_t*)ws; ws += (size_t)2048 * 8 * 2;
    ushort_t* evsw  = (ushort_t*)ws; ws += (size_t)2048 * 8 * 2;
    ushort_t* easw  = (ushort_t*)ws; ws += (size_t)256 * 8 * 2;

    const int nzero4 = N * (NHEAD + D) / 4;   // denom + ynum as float4 count

    prep_w2<<<17, 256, 0, stream>>>((const float*)d_in[26], (const float*)d_in[32],
                                    (const float*)d_in[20], eksw, evsw, easw);

    qkv_gemm<<<3 * (N / 16), 128, 0, stream>>>(key, value, query,
                                               key_w, key_b, value_w, value_b, query_w, query_b,
                                               k_ws, v_ws, q_ws,
                                               (float4*)denom_ws, nzero4, N / 16);

    edge_kernel<<<E / EPB, 256, 0, stream>>>(
        edge_feats, bidx, hidx, tidx,
        (const float*)d_in[16], (const float*)d_in[17], (const float*)d_in[18],
        (const float*)d_in[19], (const float*)d_in[21],
        (const float*)d_in[22], (const float*)d_in[23], (const float*)d_in[24],
        (const float*)d_in[25], (const float*)d_in[27],
        (const float*)d_in[28], (const float*)d_in[29], (const float*)d_in[30],
        (const float*)d_in[31], (const float*)d_in[33],
        easw, eksw, evsw,
        k_ws, q_ws, v_ws, denom_ws, ynum_ws);

    out_gemm<<<N / 16, 128, 0, stream>>>(ynum_ws, denom_ws, proj_w, proj_b, (float*)d_out);
}

// Round 4
// 414.783 us; speedup vs baseline: 1.8464x; 1.0283x over previous
//
#include <hip/hip_runtime.h>
#include <hip/hip_bf16.h>

#define D      128
#define NHEAD  8
#define FE     5
#define LSEQ   4096
#define EPB    64          // edges per block in edge_kernel
#define EPS_LN 1e-5f
#define EPS_SM 1e-16f

typedef unsigned short ushort_t;
typedef __bf16 bf16x8 __attribute__((ext_vector_type(8)));
typedef float  f32x4  __attribute__((ext_vector_type(4)));

__device__ __forceinline__ ushort_t f2bf(float x) {
    __hip_bfloat16 b = __float2bfloat16(x);
    return __builtin_bit_cast(unsigned short, b);
}

union Pk8 { ushort_t u[8]; uint4 v; };

// ---------------------------------------------------------------------------
// Prep: swizzle second-layer weights into bf16 MFMA B-fragment layout.
// Fragment f=(nt,s,l): 8 bf16 = w2[k=s*32+(l>>4)*8+j][n=nt*16+(l&15)] at dst[f*8].
// ---------------------------------------------------------------------------
__global__ __launch_bounds__(256) void prep_w2(
    const float* __restrict__ ekw2, const float* __restrict__ evw2,
    const float* __restrict__ eaw2,
    ushort_t* __restrict__ eksw, ushort_t* __restrict__ evsw,
    ushort_t* __restrict__ easw)
{
    const int g = blockIdx.x * 256 + threadIdx.x;
    const float* src; ushort_t* dst; int frag, ncols, nvalid;
    if (g < 2048)      { src = ekw2; dst = eksw; frag = g;        ncols = 128; nvalid = 128; }
    else if (g < 4096) { src = evw2; dst = evsw; frag = g - 2048; ncols = 128; nvalid = 128; }
    else if (g < 4352) { src = eaw2; dst = easw; frag = g - 4096; ncols = 8;   nvalid = 8; }
    else return;
    const int nt = frag >> 8;
    const int s  = (frag >> 6) & 3;
    const int l  = frag & 63;
    const int n  = nt * 16 + (l & 15);
    Pk8 pk;
    #pragma unroll
    for (int j = 0; j < 8; ++j) {
        const int k = s * 32 + (l >> 4) * 8 + j;
        const float v = (n < nvalid) ? src[k * ncols + n] : 0.f;
        pk.u[j] = f2bf(v);
    }
    *(uint4*)(dst + (size_t)frag * 8) = pk.v;
}

// ---------------------------------------------------------------------------
// Node projections: 3 GEMMs [N x 128] @ [128 x 128], 16 rows/block,
// transposed padded LDS (broadcast b128 reads). Also zeroes denom+ynum.
// ---------------------------------------------------------------------------
__global__ __launch_bounds__(128) void qkv_gemm(
    const float* __restrict__ key, const float* __restrict__ value,
    const float* __restrict__ query,
    const float* __restrict__ key_w, const float* __restrict__ key_b,
    const float* __restrict__ value_w, const float* __restrict__ value_b,
    const float* __restrict__ query_w, const float* __restrict__ query_b,
    float* __restrict__ k_ws, float* __restrict__ v_ws, float* __restrict__ q_ws,
    float4* __restrict__ zero_base, int nzero4,   // denom+ynum zero span
    int nb)   // blocks per matrix = N/16
{
    for (int idx = blockIdx.x * 128 + threadIdx.x; idx < nzero4; idx += gridDim.x * 128)
        zero_base[idx] = float4{0.f, 0.f, 0.f, 0.f};

    const int which = blockIdx.x / nb;
    const int r0    = (blockIdx.x % nb) * 16;
    const float* X = (which == 0) ? key   : (which == 1) ? value   : query;
    const float* W = (which == 0) ? key_w : (which == 1) ? value_w : query_w;
    const float* bias = (which == 0) ? key_b : (which == 1) ? value_b : query_b;
    float* Y = (which == 0) ? k_ws : (which == 1) ? v_ws : q_ws;

    __shared__ float xs[D][20];
    const int j = threadIdx.x;
    {
        float tmp[16];
        #pragma unroll
        for (int r = 0; r < 16; ++r) tmp[r] = X[(size_t)(r0 + r) * D + j];
        #pragma unroll
        for (int c = 0; c < 4; ++c)
            *(float4*)&xs[j][c * 4] = float4{tmp[c*4], tmp[c*4+1], tmp[c*4+2], tmp[c*4+3]};
    }
    __syncthreads();
    float acc[16];
    const float b = bias[j];
    #pragma unroll
    for (int r = 0; r < 16; ++r) acc[r] = b;
    #pragma unroll 4
    for (int i = 0; i < D; ++i) {
        const float w = W[i * D + j];
        #pragma unroll
        for (int c = 0; c < 4; ++c) {
            const float4 x4 = *(const float4*)&xs[i][c * 4];
            acc[c*4+0] = fmaf(x4.x, w, acc[c*4+0]);
            acc[c*4+1] = fmaf(x4.y, w, acc[c*4+1]);
            acc[c*4+2] = fmaf(x4.z, w, acc[c*4+2]);
            acc[c*4+3] = fmaf(x4.w, w, acc[c*4+3]);
        }
    }
    #pragma unroll
    for (int r = 0; r < 16; ++r) Y[(size_t)(r0 + r) * D + j] = acc[r];
}

// ---------------------------------------------------------------------------
// Final projection with fused normalization: Y = (num/(den+eps)) @ W + b
// ---------------------------------------------------------------------------
__global__ __launch_bounds__(128) void out_gemm(
    const float* __restrict__ num, const float* __restrict__ den,
    const float* __restrict__ W, const float* __restrict__ bias,
    float* __restrict__ Y)
{
    __shared__ float xs[D][20];
    const int j  = threadIdx.x;
    const int r0 = blockIdx.x * 16;
    {
        float tmp[16];
        #pragma unroll
        for (int r = 0; r < 16; ++r) {
            const float d = den[(size_t)(r0 + r) * NHEAD + (j >> 4)];
            tmp[r] = num[(size_t)(r0 + r) * D + j] / (d + EPS_SM);
        }
        #pragma unroll
        for (int c = 0; c < 4; ++c)
            *(float4*)&xs[j][c * 4] = float4{tmp[c*4], tmp[c*4+1], tmp[c*4+2], tmp[c*4+3]};
    }
    __syncthreads();
    float acc[16];
    const float b = bias[j];
    #pragma unroll
    for (int r = 0; r < 16; ++r) acc[r] = b;
    #pragma unroll 4
    for (int i = 0; i < D; ++i) {
        const float w = W[i * D + j];
        #pragma unroll
        for (int c = 0; c < 4; ++c) {
            const float4 x4 = *(const float4*)&xs[i][c * 4];
            acc[c*4+0] = fmaf(x4.x, w, acc[c*4+0]);
            acc[c*4+1] = fmaf(x4.y, w, acc[c*4+1]);
            acc[c*4+2] = fmaf(x4.z, w, acc[c*4+2]);
            acc[c*4+3] = fmaf(x4.w, w, acc[c*4+3]);
        }
    }
    #pragma unroll
    for (int r = 0; r < 16; ++r) Y[(size_t)(r0 + r) * D + j] = acc[r];
}

// ---------------------------------------------------------------------------
// Fused edge kernel — barrier-free wave-local pipeline.
// Block = 256 threads (4 waves), 64 edges; wave mt owns edges [mt*16, mt*16+16).
// First layer: producer lane p=4r+qt computes edge r's dims {s*32+qt*8+j},
// packs each 8-dim chunk as uint4(bf16x8); consumer lane l gets A-frag chunk s
// via 4 __shfl from lane 4*(l&15)+(l>>4). No LDS, no __syncthreads after preload.
// ---------------------------------------------------------------------------
__global__ __launch_bounds__(256, 4) void edge_kernel(
    const float* __restrict__ edge_feats,
    const int* __restrict__ bidx, const int* __restrict__ hidx, const int* __restrict__ tidx,
    const float* __restrict__ ea_w1, const float* __restrict__ ea_b1,
    const float* __restrict__ ea_g,  const float* __restrict__ ea_be, const float* __restrict__ ea_b2,
    const float* __restrict__ ek_w1, const float* __restrict__ ek_b1,
    const float* __restrict__ ek_g,  const float* __restrict__ ek_be, const float* __restrict__ ek_b2,
    const float* __restrict__ ev_w1, const float* __restrict__ ev_b1,
    const float* __restrict__ ev_g,  const float* __restrict__ ev_be, const float* __restrict__ ev_b2,
    const ushort_t* __restrict__ easw, const ushort_t* __restrict__ eksw, const ushort_t* __restrict__ evsw,
    const float* __restrict__ k_ws, const float* __restrict__ q_ws, const float* __restrict__ v_ws,
    float* __restrict__ denom_ws, float* __restrict__ ynum_ws)
{
    __shared__ float pw1[3][FE * D];
    __shared__ float pb1[3][D], pg[3][D], pbe[3][D];
    __shared__ float pb2k[D], pb2v[D], pb2a[NHEAD];
    __shared__ float ef_s[EPB][FE];
    __shared__ int   eh_s[EPB], et_s[EPB];

    const int t   = threadIdx.x;
    const int e0g = blockIdx.x * EPB;

    for (int i = t; i < FE * D; i += 256) { pw1[0][i] = ea_w1[i]; pw1[1][i] = ek_w1[i]; pw1[2][i] = ev_w1[i]; }
    if (t < D) {
        pb1[0][t] = ea_b1[t]; pb1[1][t] = ek_b1[t]; pb1[2][t] = ev_b1[t];
        pg [0][t] = ea_g [t]; pg [1][t] = ek_g [t]; pg [2][t] = ev_g [t];
        pbe[0][t] = ea_be[t]; pbe[1][t] = ek_be[t]; pbe[2][t] = ev_be[t];
        pb2k[t] = ek_b2[t];   pb2v[t] = ev_b2[t];
        if (t < NHEAD) pb2a[t] = ea_b2[t];
    }
    for (int i = t; i < EPB * FE; i += 256) ((float*)ef_s)[i] = edge_feats[(size_t)e0g * FE + i];
    if (t < EPB) {
        const int bb = bidx[e0g + t];
        eh_s[t] = bb * LSEQ + hidx[e0g + t];
        et_s[t] = bb * LSEQ + tidx[e0g + t];
    }
    __syncthreads();     // the only barrier

    const int mt   = t >> 6;        // wave id == m-tile
    const int l    = t & 63;        // lane
    const int qt   = l & 3;         // producer: dim-chunk quarter
    const int per  = l >> 2;        // producer: edge row 0..15
    const int row0 = (l >> 4) * 4;  // consumer: accumulator row base
    const int colb = l & 15;        // consumer: column within n-tile
    const int src  = 4 * colb + (l >> 4);   // shfl source for A-frag chunks
    const int bsrc = (l & 48);      // row-group base for ea/ex broadcasts

    int tn[4], hnn[4];
    #pragma unroll
    for (int r = 0; r < 4; ++r) { tn[r] = et_s[mt*16 + row0 + r]; hnn[r] = eh_s[mt*16 + row0 + r]; }

    float efr[FE];
    #pragma unroll
    for (int f = 0; f < FE; ++f) efr[f] = ef_s[mt*16 + per][f];

    // ---- first layer + LN -> packed bf16 chunks in registers ----
    auto first_layer = [&](int m, uint4 pk[4]) {
        const float4* w1v = (const float4*)&pw1[m][0];
        const float4* b1v = (const float4*)&pb1[m][0];
        const float4* gv  = (const float4*)&pg[m][0];
        const float4* bev = (const float4*)&pbe[m][0];
        float4 hv[4][2];
        float s1 = 0.f, s2 = 0.f;
        #pragma unroll
        for (int s = 0; s < 4; ++s) {
            #pragma unroll
            for (int hc = 0; hc < 2; ++hc) {
                const int idx = s * 8 + qt * 2 + hc;
                float4 a = b1v[idx];
                #pragma unroll
                for (int f = 0; f < FE; ++f) {
                    const float sc = efr[f];
                    const float4 w = w1v[f * 32 + idx];
                    a.x = fmaf(sc, w.x, a.x); a.y = fmaf(sc, w.y, a.y);
                    a.z = fmaf(sc, w.z, a.z); a.w = fmaf(sc, w.w, a.w);
                }
                a.x = fmaxf(a.x, 0.f); a.y = fmaxf(a.y, 0.f);
                a.z = fmaxf(a.z, 0.f); a.w = fmaxf(a.w, 0.f);
                hv[s][hc] = a;
                s1 += a.x + a.y + a.z + a.w;
                s2 += a.x*a.x + a.y*a.y + a.z*a.z + a.w*a.w;
            }
        }
        s1 += __shfl_xor(s1, 1); s1 += __shfl_xor(s1, 2);
        s2 += __shfl_xor(s2, 1); s2 += __shfl_xor(s2, 2);
        const float mu = s1 * (1.f / 128.f);
        const float rs = rsqrtf(s2 * (1.f / 128.f) - mu * mu + EPS_LN);
        #pragma unroll
        for (int s = 0; s < 4; ++s) {
            const int idx = s * 8 + qt * 2;
            const float4 x0 = hv[s][0], x1 = hv[s][1];
            const float4 g0 = gv[idx], g1 = gv[idx + 1];
            const float4 b0 = bev[idx], b1 = bev[idx + 1];
            Pk8 p8;
            p8.u[0] = f2bf(fmaf((x0.x - mu) * rs, g0.x, b0.x));
            p8.u[1] = f2bf(fmaf((x0.y - mu) * rs, g0.y, b0.y));
            p8.u[2] = f2bf(fmaf((x0.z - mu) * rs, g0.z, b0.z));
            p8.u[3] = f2bf(fmaf((x0.w - mu) * rs, g0.w, b0.w));
            p8.u[4] = f2bf(fmaf((x1.x - mu) * rs, g1.x, b1.x));
            p8.u[5] = f2bf(fmaf((x1.y - mu) * rs, g1.y, b1.y));
            p8.u[6] = f2bf(fmaf((x1.z - mu) * rs, g1.z, b1.z));
            p8.u[7] = f2bf(fmaf((x1.w - mu) * rs, g1.w, b1.w));
            pk[s] = p8.v;
        }
    };

    auto gather_afr = [&](const uint4 pk[4], bf16x8 afr[4]) {
        #pragma unroll
        for (int s = 0; s < 4; ++s) {
            uint4 w;
            w.x = (unsigned)__shfl((int)pk[s].x, src);
            w.y = (unsigned)__shfl((int)pk[s].y, src);
            w.z = (unsigned)__shfl((int)pk[s].z, src);
            w.w = (unsigned)__shfl((int)pk[s].w, src);
            afr[s] = __builtin_bit_cast(bf16x8, w);
        }
    };

    uint4 pk[4];
    bf16x8 afr[4];

    // ================= MLP 0: ea (attention bias, cols padded 8->16) ========
    float eaacc[4];
    first_layer(0, pk);
    gather_afr(pk, afr);
    {
        f32x4 acc = {0.f, 0.f, 0.f, 0.f};
        #pragma unroll
        for (int s = 0; s < 4; ++s) {
            const bf16x8 bfr = *(const bf16x8*)(easw + (size_t)(s * 64 + l) * 8);
            acc = __builtin_amdgcn_mfma_f32_16x16x32_bf16(afr[s], bfr, acc, 0, 0, 0);
        }
        #pragma unroll
        for (int r = 0; r < 4; ++r) eaacc[r] = acc[r];   // raw; bias added later
    }

    // ================= MLP 1: ek -> scores -> exp -> denom ==================
    float exsel[4] = {0.f, 0.f, 0.f, 0.f};
    first_layer(1, pk);
    gather_afr(pk, afr);
    #pragma unroll
    for (int nt = 0; nt < NHEAD; ++nt) {
        f32x4 acc = {0.f, 0.f, 0.f, 0.f};
        #pragma unroll
        for (int s = 0; s < 4; ++s) {
            const bf16x8 bfr = *(const bf16x8*)(eksw + (size_t)((nt * 4 + s) * 64 + l) * 8);
            acc = __builtin_amdgcn_mfma_f32_16x16x32_bf16(afr[s], bfr, acc, 0, 0, 0);
        }
        const int col = nt * 16 + colb;
        const float b2 = pb2k[col];
        const float ba = pb2a[nt];
        float pr[4];
        #pragma unroll
        for (int r = 0; r < 4; ++r)
            pr[r] = (acc[r] + b2 + k_ws[(size_t)tn[r] * D + col]) * q_ws[(size_t)hnn[r] * D + col];
        #pragma unroll
        for (int m = 1; m < 16; m <<= 1) {
            #pragma unroll
            for (int r = 0; r < 4; ++r) pr[r] += __shfl_xor(pr[r], m);
        }
        #pragma unroll
        for (int r = 0; r < 4; ++r) {
            // segment-max skipped: |score| small, exp cannot overflow.
            const float ea = __shfl(eaacc[r], bsrc | nt);
            const float ex = __expf(pr[r] + ea + ba);
            if (colb == nt) {
                exsel[r] = ex;
                atomicAdd(&denom_ws[(size_t)hnn[r] * NHEAD + nt], ex);
            }
        }
    }

    // ================= MLP 2: ev -> weighted scatter (unnormalized) =========
    first_layer(2, pk);
    gather_afr(pk, afr);
    #pragma unroll
    for (int nt = 0; nt < NHEAD; ++nt) {
        f32x4 acc = {0.f, 0.f, 0.f, 0.f};
        #pragma unroll
        for (int s = 0; s < 4; ++s) {
            const bf16x8 bfr = *(const bf16x8*)(evsw + (size_t)((nt * 4 + s) * 64 + l) * 8);
            acc = __builtin_amdgcn_mfma_f32_16x16x32_bf16(afr[s], bfr, acc, 0, 0, 0);
        }
        const int col = nt * 16 + colb;
        const float b2 = pb2v[col];
        #pragma unroll
        for (int r = 0; r < 4; ++r) {
            const float exb = __shfl(exsel[r], bsrc | nt);
            const float vs  = acc[r] + b2 + v_ws[(size_t)tn[r] * D + col];
            atomicAdd(&ynum_ws[(size_t)hnn[r] * D + col], exb * vs);
        }
    }
}

// ---------------------------------------------------------------------------
extern "C" void kernel_launch(void* const* d_in, const int* in_sizes, int n_in,
                              void* d_out, int out_size, void* d_ws, size_t ws_size,
                              hipStream_t stream)
{
    const float* key        = (const float*)d_in[0];
    const float* value      = (const float*)d_in[1];
    const float* query      = (const float*)d_in[2];
    const float* edge_feats = (const float*)d_in[3];
    const int*   bidx       = (const int*)d_in[5];
    const int*   hidx       = (const int*)d_in[6];
    const int*   tidx       = (const int*)d_in[7];
    const float* key_w   = (const float*)d_in[8];  const float* key_b   = (const float*)d_in[9];
    const float* query_w = (const float*)d_in[10]; const float* query_b = (const float*)d_in[11];
    const float* value_w = (const float*)d_in[12]; const float* value_b = (const float*)d_in[13];
    const float* proj_w  = (const float*)d_in[14]; const float* proj_b  = (const float*)d_in[15];

    const int N = in_sizes[0] / D;   // 16384 nodes
    const int E = in_sizes[5];       // 262144 edges

    char* ws = (char*)d_ws;
    float* k_ws     = (float*)ws;  ws += (size_t)N * D * 4;
    float* q_ws     = (float*)ws;  ws += (size_t)N * D * 4;
    float* v_ws     = (float*)ws;  ws += (size_t)N * D * 4;
    float* denom_ws = (float*)ws;  ws += (size_t)N * NHEAD * 4;
    float* ynum_ws  = (float*)ws;  ws += (size_t)N * D * 4;     // contiguous after denom
    ushort_t* eksw  = (ushort_t*)ws; ws += (size_t)2048 * 8 * 2;
    ushort_t* evsw  = (ushort_t*)ws; ws += (size_t)2048 * 8 * 2;
    ushort_t* easw  = (ushort_t*)ws; ws += (size_t)256 * 8 * 2;

    const int nzero4 = N * (NHEAD + D) / 4;   // denom + ynum as float4 count

    prep_w2<<<17, 256, 0, stream>>>((const float*)d_in[26], (const float*)d_in[32],
                                    (const float*)d_in[20], eksw, evsw, easw);

    qkv_gemm<<<3 * (N / 16), 128, 0, stream>>>(key, value, query,
                                               key_w, key_b, value_w, value_b, query_w, query_b,
                                               k_ws, v_ws, q_ws,
                                               (float4*)denom_ws, nzero4, N / 16);

    edge_kernel<<<E / EPB, 256, 0, stream>>>(
        edge_feats, bidx, hidx, tidx,
        (const float*)d_in[16], (const float*)d_in[17], (const float*)d_in[18],
        (const float*)d_in[19], (const float*)d_in[21],
        (const float*)d_in[22], (const float*)d_in[23], (const float*)d_in[24],
        (const float*)d_in[25], (const float*)d_in[27],
        (const float*)d_in[28], (const float*)d_in[29], (const float*)d_in[30],
        (const float*)d_in[31], (const float*)d_in[33],
        easw, eksw, evsw,
        k_ws, q_ws, v_ws, denom_ws, ynum_ws);

    out_gemm<<<N / 16, 128, 0, stream>>>(ynum_ws, denom_ws, proj_w, proj_b, (float*)d_out);
}

// Round 5
// 349.017 us; speedup vs baseline: 2.1943x; 1.1884x over previous
//
#include <hip/hip_runtime.h>
#include <hip/hip_bf16.h>

#define D      128
#define NHEAD  8
#define FE     5
#define LSEQ   4096
#define EPB    64          // edges per block in edge_kernel
#define NNODE  16384
#define EPS_LN 1e-5f
#define EPS_SM 1e-16f

typedef unsigned short ushort_t;
typedef __bf16 bf16x8 __attribute__((ext_vector_type(8)));
typedef float  f32x4  __attribute__((ext_vector_type(4)));

__device__ __forceinline__ ushort_t f2bf(float x) {
    __hip_bfloat16 b = __float2bfloat16(x);
    return __builtin_bit_cast(unsigned short, b);
}
__device__ __forceinline__ float bf2f(ushort_t u) {
    __hip_bfloat16 b = __builtin_bit_cast(__hip_bfloat16, u);
    return __bfloat162float(b);
}

union Pk8 { ushort_t u[8]; uint4 v; };

// ---------------------------------------------------------------------------
// Prep: swizzle second-layer weights into bf16 MFMA B-fragment layout,
// and zero the CSR histogram counters.
// ---------------------------------------------------------------------------
__global__ __launch_bounds__(256) void prep_w2(
    const float* __restrict__ ekw2, const float* __restrict__ evw2,
    const float* __restrict__ eaw2,
    ushort_t* __restrict__ eksw, ushort_t* __restrict__ evsw,
    ushort_t* __restrict__ easw, int* __restrict__ cnt)
{
    const int g = blockIdx.x * 256 + threadIdx.x;
    for (int i = g; i < NNODE; i += gridDim.x * 256) cnt[i] = 0;

    const float* src; ushort_t* dst; int frag, ncols, nvalid;
    if (g < 2048)      { src = ekw2; dst = eksw; frag = g;        ncols = 128; nvalid = 128; }
    else if (g < 4096) { src = evw2; dst = evsw; frag = g - 2048; ncols = 128; nvalid = 128; }
    else if (g < 4352) { src = eaw2; dst = easw; frag = g - 4096; ncols = 8;   nvalid = 8; }
    else return;
    const int s  = (frag >> 6) & 3;
    const int l  = frag & 63;
    const int n  = ((frag >> 8) << 4) + (l & 15);
    Pk8 pk;
    #pragma unroll
    for (int j = 0; j < 8; ++j) {
        const int k = s * 32 + (l >> 4) * 8 + j;
        const float v = (n < nvalid) ? src[k * ncols + n] : 0.f;
        pk.u[j] = f2bf(v);
    }
    *(uint4*)(dst + (size_t)frag * 8) = pk.v;
}

// ---------------------------------------------------------------------------
// CSR build: histogram -> scan -> scatter (edge order within segment arbitrary)
// ---------------------------------------------------------------------------
__global__ __launch_bounds__(256) void build_hist(
    const int* __restrict__ bidx, const int* __restrict__ hidx,
    int* __restrict__ cnt, int E)
{
    const int e = blockIdx.x * 256 + threadIdx.x;
    if (e < E) atomicAdd(&cnt[bidx[e] * LSEQ + hidx[e]], 1);
}

__global__ __launch_bounds__(1024) void scan16k(
    const int* __restrict__ cnt, int* __restrict__ base)
{
    __shared__ int part[1024];
    const int t = threadIdx.x;
    int v[16], ex[16], s = 0;
    #pragma unroll
    for (int i = 0; i < 16; ++i) v[i] = cnt[t * 16 + i];
    #pragma unroll
    for (int i = 0; i < 16; ++i) { ex[i] = s; s += v[i]; }
    part[t] = s;
    __syncthreads();
    for (int off = 1; off < 1024; off <<= 1) {
        const int x = (t >= off) ? part[t - off] : 0;
        __syncthreads();
        part[t] += x;
        __syncthreads();
    }
    const int boff = (t > 0) ? part[t - 1] : 0;
    #pragma unroll
    for (int i = 0; i < 16; ++i) base[t * 16 + i] = boff + ex[i];
    if (t == 1023) base[NNODE] = boff + s;
}

__global__ __launch_bounds__(256) void scatter_order(
    const int* __restrict__ bidx, const int* __restrict__ hidx,
    const int* __restrict__ base, int* __restrict__ cnt,
    int* __restrict__ order, int E)
{
    const int e = blockIdx.x * 256 + threadIdx.x;
    if (e < E) {
        const int nh = bidx[e] * LSEQ + hidx[e];
        const int slot = atomicSub(&cnt[nh], 1) - 1;
        order[base[nh] + slot] = e;
    }
}

// ---------------------------------------------------------------------------
// Node projections: 3 GEMMs [N x 128] @ [128 x 128], 16 rows/block.
// ---------------------------------------------------------------------------
__global__ __launch_bounds__(128) void qkv_gemm(
    const float* __restrict__ key, const float* __restrict__ value,
    const float* __restrict__ query,
    const float* __restrict__ key_w, const float* __restrict__ key_b,
    const float* __restrict__ value_w, const float* __restrict__ value_b,
    const float* __restrict__ query_w, const float* __restrict__ query_b,
    float* __restrict__ k_ws, float* __restrict__ v_ws, float* __restrict__ q_ws,
    int nb)   // blocks per matrix = N/16
{
    const int which = blockIdx.x / nb;
    const int r0    = (blockIdx.x % nb) * 16;
    const float* X = (which == 0) ? key   : (which == 1) ? value   : query;
    const float* W = (which == 0) ? key_w : (which == 1) ? value_w : query_w;
    const float* bias = (which == 0) ? key_b : (which == 1) ? value_b : query_b;
    float* Y = (which == 0) ? k_ws : (which == 1) ? v_ws : q_ws;

    __shared__ float xs[D][20];
    const int j = threadIdx.x;
    {
        float tmp[16];
        #pragma unroll
        for (int r = 0; r < 16; ++r) tmp[r] = X[(size_t)(r0 + r) * D + j];
        #pragma unroll
        for (int c = 0; c < 4; ++c)
            *(float4*)&xs[j][c * 4] = float4{tmp[c*4], tmp[c*4+1], tmp[c*4+2], tmp[c*4+3]};
    }
    __syncthreads();
    float acc[16];
    const float b = bias[j];
    #pragma unroll
    for (int r = 0; r < 16; ++r) acc[r] = b;
    #pragma unroll 4
    for (int i = 0; i < D; ++i) {
        const float w = W[i * D + j];
        #pragma unroll
        for (int c = 0; c < 4; ++c) {
            const float4 x4 = *(const float4*)&xs[i][c * 4];
            acc[c*4+0] = fmaf(x4.x, w, acc[c*4+0]);
            acc[c*4+1] = fmaf(x4.y, w, acc[c*4+1]);
            acc[c*4+2] = fmaf(x4.z, w, acc[c*4+2]);
            acc[c*4+3] = fmaf(x4.w, w, acc[c*4+3]);
        }
    }
    #pragma unroll
    for (int r = 0; r < 16; ++r) Y[(size_t)(r0 + r) * D + j] = acc[r];
}

// ---------------------------------------------------------------------------
// Final projection: Y = ynorm @ W + b   (ynorm already normalized by agg)
// ---------------------------------------------------------------------------
__global__ __launch_bounds__(128) void out_gemm(
    const float* __restrict__ num, const float* __restrict__ W,
    const float* __restrict__ bias, float* __restrict__ Y)
{
    __shared__ float xs[D][20];
    const int j  = threadIdx.x;
    const int r0 = blockIdx.x * 16;
    {
        float tmp[16];
        #pragma unroll
        for (int r = 0; r < 16; ++r) tmp[r] = num[(size_t)(r0 + r) * D + j];
        #pragma unroll
        for (int c = 0; c < 4; ++c)
            *(float4*)&xs[j][c * 4] = float4{tmp[c*4], tmp[c*4+1], tmp[c*4+2], tmp[c*4+3]};
    }
    __syncthreads();
    float acc[16];
    const float b = bias[j];
    #pragma unroll
    for (int r = 0; r < 16; ++r) acc[r] = b;
    #pragma unroll 4
    for (int i = 0; i < D; ++i) {
        const float w = W[i * D + j];
        #pragma unroll
        for (int c = 0; c < 4; ++c) {
            const float4 x4 = *(const float4*)&xs[i][c * 4];
            acc[c*4+0] = fmaf(x4.x, w, acc[c*4+0]);
            acc[c*4+1] = fmaf(x4.y, w, acc[c*4+1]);
            acc[c*4+2] = fmaf(x4.z, w, acc[c*4+2]);
            acc[c*4+3] = fmaf(x4.w, w, acc[c*4+3]);
        }
    }
    #pragma unroll
    for (int r = 0; r < 16; ++r) Y[(size_t)(r0 + r) * D + j] = acc[r];
}

// ---------------------------------------------------------------------------
// Fused edge kernel — barrier-free wave-local pipeline, NO atomics.
// Writes per-edge ex (f32 [E][8]) and raw vs (bf16 [E][128]).
// ---------------------------------------------------------------------------
__global__ __launch_bounds__(256, 4) void edge_kernel(
    const float* __restrict__ edge_feats,
    const int* __restrict__ bidx, const int* __restrict__ hidx, const int* __restrict__ tidx,
    const float* __restrict__ ea_w1, const float* __restrict__ ea_b1,
    const float* __restrict__ ea_g,  const float* __restrict__ ea_be, const float* __restrict__ ea_b2,
    const float* __restrict__ ek_w1, const float* __restrict__ ek_b1,
    const float* __restrict__ ek_g,  const float* __restrict__ ek_be, const float* __restrict__ ek_b2,
    const float* __restrict__ ev_w1, const float* __restrict__ ev_b1,
    const float* __restrict__ ev_g,  const float* __restrict__ ev_be, const float* __restrict__ ev_b2,
    const ushort_t* __restrict__ easw, const ushort_t* __restrict__ eksw, const ushort_t* __restrict__ evsw,
    const float* __restrict__ k_ws, const float* __restrict__ q_ws, const float* __restrict__ v_ws,
    float* __restrict__ ex_ws, ushort_t* __restrict__ vs_ws)
{
    __shared__ float pw1[3][FE * D];
    __shared__ float pb1[3][D], pg[3][D], pbe[3][D];
    __shared__ float pb2k[D], pb2v[D], pb2a[NHEAD];
    __shared__ float ef_s[EPB][FE];
    __shared__ int   eh_s[EPB], et_s[EPB];

    const int t   = threadIdx.x;
    const int e0g = blockIdx.x * EPB;

    for (int i = t; i < FE * D; i += 256) { pw1[0][i] = ea_w1[i]; pw1[1][i] = ek_w1[i]; pw1[2][i] = ev_w1[i]; }
    if (t < D) {
        pb1[0][t] = ea_b1[t]; pb1[1][t] = ek_b1[t]; pb1[2][t] = ev_b1[t];
        pg [0][t] = ea_g [t]; pg [1][t] = ek_g [t]; pg [2][t] = ev_g [t];
        pbe[0][t] = ea_be[t]; pbe[1][t] = ek_be[t]; pbe[2][t] = ev_be[t];
        pb2k[t] = ek_b2[t];   pb2v[t] = ev_b2[t];
        if (t < NHEAD) pb2a[t] = ea_b2[t];
    }
    for (int i = t; i < EPB * FE; i += 256) ((float*)ef_s)[i] = edge_feats[(size_t)e0g * FE + i];
    if (t < EPB) {
        const int bb = bidx[e0g + t];
        eh_s[t] = bb * LSEQ + hidx[e0g + t];
        et_s[t] = bb * LSEQ + tidx[e0g + t];
    }
    __syncthreads();     // the only barrier

    const int mt   = t >> 6;        // wave id == m-tile
    const int l    = t & 63;        // lane
    const int qt   = l & 3;         // producer: dim-chunk quarter
    const int per  = l >> 2;        // producer: edge row 0..15
    const int row0 = (l >> 4) * 4;  // consumer: accumulator row base
    const int colb = l & 15;        // consumer: column within n-tile
    const int src  = 4 * colb + (l >> 4);   // shfl source for A-frag chunks
    const int bsrc = (l & 48);      // row-group base for ea broadcasts

    int tn[4], hnn[4];
    #pragma unroll
    for (int r = 0; r < 4; ++r) { tn[r] = et_s[mt*16 + row0 + r]; hnn[r] = eh_s[mt*16 + row0 + r]; }

    float efr[FE];
    #pragma unroll
    for (int f = 0; f < FE; ++f) efr[f] = ef_s[mt*16 + per][f];

    auto first_layer = [&](int m, uint4 pk[4]) {
        const float4* w1v = (const float4*)&pw1[m][0];
        const float4* b1v = (const float4*)&pb1[m][0];
        const float4* gv  = (const float4*)&pg[m][0];
        const float4* bev = (const float4*)&pbe[m][0];
        float4 hv[4][2];
        float s1 = 0.f, s2 = 0.f;
        #pragma unroll
        for (int s = 0; s < 4; ++s) {
            #pragma unroll
            for (int hc = 0; hc < 2; ++hc) {
                const int idx = s * 8 + qt * 2 + hc;
                float4 a = b1v[idx];
                #pragma unroll
                for (int f = 0; f < FE; ++f) {
                    const float sc = efr[f];
                    const float4 w = w1v[f * 32 + idx];
                    a.x = fmaf(sc, w.x, a.x); a.y = fmaf(sc, w.y, a.y);
                    a.z = fmaf(sc, w.z, a.z); a.w = fmaf(sc, w.w, a.w);
                }
                a.x = fmaxf(a.x, 0.f); a.y = fmaxf(a.y, 0.f);
                a.z = fmaxf(a.z, 0.f); a.w = fmaxf(a.w, 0.f);
                hv[s][hc] = a;
                s1 += a.x + a.y + a.z + a.w;
                s2 += a.x*a.x + a.y*a.y + a.z*a.z + a.w*a.w;
            }
        }
        s1 += __shfl_xor(s1, 1); s1 += __shfl_xor(s1, 2);
        s2 += __shfl_xor(s2, 1); s2 += __shfl_xor(s2, 2);
        const float mu = s1 * (1.f / 128.f);
        const float rs = rsqrtf(s2 * (1.f / 128.f) - mu * mu + EPS_LN);
        #pragma unroll
        for (int s = 0; s < 4; ++s) {
            const int idx = s * 8 + qt * 2;
            const float4 x0 = hv[s][0], x1 = hv[s][1];
            const float4 g0 = gv[idx], g1 = gv[idx + 1];
            const float4 b0 = bev[idx], b1 = bev[idx + 1];
            Pk8 p8;
            p8.u[0] = f2bf(fmaf((x0.x - mu) * rs, g0.x, b0.x));
            p8.u[1] = f2bf(fmaf((x0.y - mu) * rs, g0.y, b0.y));
            p8.u[2] = f2bf(fmaf((x0.z - mu) * rs, g0.z, b0.z));
            p8.u[3] = f2bf(fmaf((x0.w - mu) * rs, g0.w, b0.w));
            p8.u[4] = f2bf(fmaf((x1.x - mu) * rs, g1.x, b1.x));
            p8.u[5] = f2bf(fmaf((x1.y - mu) * rs, g1.y, b1.y));
            p8.u[6] = f2bf(fmaf((x1.z - mu) * rs, g1.z, b1.z));
            p8.u[7] = f2bf(fmaf((x1.w - mu) * rs, g1.w, b1.w));
            pk[s] = p8.v;
        }
    };

    auto gather_afr = [&](const uint4 pk[4], bf16x8 afr[4]) {
        #pragma unroll
        for (int s = 0; s < 4; ++s) {
            uint4 w;
            w.x = (unsigned)__shfl((int)pk[s].x, src);
            w.y = (unsigned)__shfl((int)pk[s].y, src);
            w.z = (unsigned)__shfl((int)pk[s].z, src);
            w.w = (unsigned)__shfl((int)pk[s].w, src);
            afr[s] = __builtin_bit_cast(bf16x8, w);
        }
    };

    uint4 pk[4];
    bf16x8 afr[4];

    // ================= MLP 0: ea (attention bias, cols padded 8->16) ========
    float eaacc[4];
    first_layer(0, pk);
    gather_afr(pk, afr);
    {
        f32x4 acc = {0.f, 0.f, 0.f, 0.f};
        #pragma unroll
        for (int s = 0; s < 4; ++s) {
            const bf16x8 bfr = *(const bf16x8*)(easw + (size_t)(s * 64 + l) * 8);
            acc = __builtin_amdgcn_mfma_f32_16x16x32_bf16(afr[s], bfr, acc, 0, 0, 0);
        }
        #pragma unroll
        for (int r = 0; r < 4; ++r) eaacc[r] = acc[r];   // raw; bias added later
    }

    // ================= MLP 1: ek -> scores -> exp -> ex_ws ==================
    first_layer(1, pk);
    gather_afr(pk, afr);
    #pragma unroll
    for (int nt = 0; nt < NHEAD; ++nt) {
        f32x4 acc = {0.f, 0.f, 0.f, 0.f};
        #pragma unroll
        for (int s = 0; s < 4; ++s) {
            const bf16x8 bfr = *(const bf16x8*)(eksw + (size_t)((nt * 4 + s) * 64 + l) * 8);
            acc = __builtin_amdgcn_mfma_f32_16x16x32_bf16(afr[s], bfr, acc, 0, 0, 0);
        }
        const int col = nt * 16 + colb;
        const float b2 = pb2k[col];
        const float ba = pb2a[nt];
        float pr[4];
        #pragma unroll
        for (int r = 0; r < 4; ++r)
            pr[r] = (acc[r] + b2 + k_ws[(size_t)tn[r] * D + col]) * q_ws[(size_t)hnn[r] * D + col];
        #pragma unroll
        for (int m = 1; m < 16; m <<= 1) {
            #pragma unroll
            for (int r = 0; r < 4; ++r) pr[r] += __shfl_xor(pr[r], m);
        }
        #pragma unroll
        for (int r = 0; r < 4; ++r) {
            // segment-max skipped: |score| small, exp cannot overflow.
            const float ea = __shfl(eaacc[r], bsrc | nt);
            const float ex = __expf(pr[r] + ea + ba);
            if (colb == nt)
                ex_ws[(size_t)(e0g + mt*16 + row0 + r) * NHEAD + nt] = ex;
        }
    }

    // ================= MLP 2: ev -> raw vs (bf16) ===========================
    first_layer(2, pk);
    gather_afr(pk, afr);
    #pragma unroll
    for (int nt = 0; nt < NHEAD; ++nt) {
        f32x4 acc = {0.f, 0.f, 0.f, 0.f};
        #pragma unroll
        for (int s = 0; s < 4; ++s) {
            const bf16x8 bfr = *(const bf16x8*)(evsw + (size_t)((nt * 4 + s) * 64 + l) * 8);
            acc = __builtin_amdgcn_mfma_f32_16x16x32_bf16(afr[s], bfr, acc, 0, 0, 0);
        }
        const int col = nt * 16 + colb;
        const float b2 = pb2v[col];
        #pragma unroll
        for (int r = 0; r < 4; ++r) {
            const float vs = acc[r] + b2 + v_ws[(size_t)tn[r] * D + col];
            vs_ws[(size_t)(e0g + mt*16 + row0 + r) * D + col] = f2bf(vs);
        }
    }
}

// ---------------------------------------------------------------------------
// Aggregation: one block per head node, walk CSR segment, no atomics.
// y[n][j] = sum_e ex[e][j/16] * vs[e][j] / (sum_e ex[e][j/16] + eps)
// ---------------------------------------------------------------------------
__global__ __launch_bounds__(128) void agg_kernel(
    const int* __restrict__ order, const int* __restrict__ base,
    const float* __restrict__ ex_ws, const ushort_t* __restrict__ vs_ws,
    float* __restrict__ y_ws)
{
    const int n  = blockIdx.x;
    const int j  = threadIdx.x;
    const int h  = j >> 4;
    const int s0 = base[n], s1 = base[n + 1];

    float acc = 0.f, den = 0.f;
    for (int i = s0; i < s1; i += 4) {
        const int m = s1 - i;
        int   e[4];
        float exv[4], vsv[4];
        #pragma unroll
        for (int r = 0; r < 4; ++r) if (r < m) e[r] = order[i + r];
        #pragma unroll
        for (int r = 0; r < 4; ++r) if (r < m) {
            exv[r] = ex_ws[(size_t)e[r] * NHEAD + h];
            vsv[r] = bf2f(vs_ws[(size_t)e[r] * D + j]);
        }
        #pragma unroll
        for (int r = 0; r < 4; ++r) if (r < m) {
            den += exv[r];
            acc = fmaf(exv[r], vsv[r], acc);
        }
    }
    y_ws[(size_t)n * D + j] = acc / (den + EPS_SM);
}

// ---------------------------------------------------------------------------
extern "C" void kernel_launch(void* const* d_in, const int* in_sizes, int n_in,
                              void* d_out, int out_size, void* d_ws, size_t ws_size,
                              hipStream_t stream)
{
    const float* key        = (const float*)d_in[0];
    const float* value      = (const float*)d_in[1];
    const float* query      = (const float*)d_in[2];
    const float* edge_feats = (const float*)d_in[3];
    const int*   bidx       = (const int*)d_in[5];
    const int*   hidx       = (const int*)d_in[6];
    const int*   tidx       = (const int*)d_in[7];
    const float* key_w   = (const float*)d_in[8];  const float* key_b   = (const float*)d_in[9];
    const float* query_w = (const float*)d_in[10]; const float* query_b = (const float*)d_in[11];
    const float* value_w = (const float*)d_in[12]; const float* value_b = (const float*)d_in[13];
    const float* proj_w  = (const float*)d_in[14]; const float* proj_b  = (const float*)d_in[15];

    const int N = in_sizes[0] / D;   // 16384 nodes
    const int E = in_sizes[5];       // 262144 edges

    char* ws = (char*)d_ws;
    float* k_ws   = (float*)ws;  ws += (size_t)N * D * 4;
    float* q_ws   = (float*)ws;  ws += (size_t)N * D * 4;
    float* v_ws   = (float*)ws;  ws += (size_t)N * D * 4;
    float* y_ws   = (float*)ws;  ws += (size_t)N * D * 4;
    float* ex_ws  = (float*)ws;  ws += (size_t)E * NHEAD * 4;
    ushort_t* vs_ws = (ushort_t*)ws; ws += (size_t)E * D * 2;
    ushort_t* eksw  = (ushort_t*)ws; ws += (size_t)2048 * 8 * 2;
    ushort_t* evsw  = (ushort_t*)ws; ws += (size_t)2048 * 8 * 2;
    ushort_t* easw  = (ushort_t*)ws; ws += (size_t)256 * 8 * 2;
    int* order = (int*)ws;  ws += (size_t)E * 4;
    int* base  = (int*)ws;  ws += (size_t)(N + 1) * 4;
    int* cnt   = (int*)ws;  ws += (size_t)N * 4;

    // --- CSR build (head->edges) ---
    prep_w2<<<17, 256, 0, stream>>>((const float*)d_in[26], (const float*)d_in[32],
                                    (const float*)d_in[20], eksw, evsw, easw, cnt);
    build_hist<<<(E + 255) / 256, 256, 0, stream>>>(bidx, hidx, cnt, E);
    scan16k<<<1, 1024, 0, stream>>>(cnt, base);
    scatter_order<<<(E + 255) / 256, 256, 0, stream>>>(bidx, hidx, base, cnt, order, E);

    qkv_gemm<<<3 * (N / 16), 128, 0, stream>>>(key, value, query,
                                               key_w, key_b, value_w, value_b, query_w, query_b,
                                               k_ws, v_ws, q_ws, N / 16);

    edge_kernel<<<E / EPB, 256, 0, stream>>>(
        edge_feats, bidx, hidx, tidx,
        (const float*)d_in[16], (const float*)d_in[17], (const float*)d_in[18],
        (const float*)d_in[19], (const float*)d_in[21],
        (const float*)d_in[22], (const float*)d_in[23], (const float*)d_in[24],
        (const float*)d_in[25], (const float*)d_in[27],
        (const float*)d_in[28], (const float*)d_in[29], (const float*)d_in[30],
        (const float*)d_in[31], (const float*)d_in[33],
        easw, eksw, evsw,
        k_ws, q_ws, v_ws, ex_ws, vs_ws);

    agg_kernel<<<N, 128, 0, stream>>>(order, base, ex_ws, vs_ws, y_ws);

    out_gemm<<<N / 16, 128, 0, stream>>>(y_ws, proj_w, proj_b, (float*)d_out);
}

// Round 6
// 321.869 us; speedup vs baseline: 2.3794x; 1.0843x over previous
//
#include <hip/hip_runtime.h>
#include <hip/hip_bf16.h>

#define D      128
#define NHEAD  8
#define FE     5
#define LSEQ   4096
#define EPB    64          // edges per block in edge_kernel
#define NNODE  16384
#define EPS_LN 1e-5f
#define EPS_SM 1e-16f

typedef unsigned short ushort_t;
typedef __bf16 bf16x8 __attribute__((ext_vector_type(8)));
typedef float  f32x4  __attribute__((ext_vector_type(4)));

__device__ __forceinline__ ushort_t f2bf(float x) {
    __hip_bfloat16 b = __float2bfloat16(x);
    return __builtin_bit_cast(unsigned short, b);
}
__device__ __forceinline__ float bf2f(ushort_t u) {
    __hip_bfloat16 b = __builtin_bit_cast(__hip_bfloat16, u);
    return __bfloat162float(b);
}

union Pk8 { ushort_t u[8]; uint4 v; };

// ---------------------------------------------------------------------------
// setup_kernel: three independent jobs partitioned by blockIdx
//   [0, 3*nqb)        : qkv GEMMs, 32 rows/block, bf16 output
//   [3*nqb, +17)      : w2 swizzle into MFMA B-fragment layout
//   [3*nqb+17, +1024) : head histogram (cnt pre-zeroed by memset)
// ---------------------------------------------------------------------------
__global__ __launch_bounds__(256) void setup_kernel(
    const float* __restrict__ key, const float* __restrict__ value,
    const float* __restrict__ query,
    const float* __restrict__ key_w, const float* __restrict__ key_b,
    const float* __restrict__ value_w, const float* __restrict__ value_b,
    const float* __restrict__ query_w, const float* __restrict__ query_b,
    ushort_t* __restrict__ k16, ushort_t* __restrict__ v16, ushort_t* __restrict__ q16,
    const float* __restrict__ ekw2, const float* __restrict__ evw2,
    const float* __restrict__ eaw2,
    ushort_t* __restrict__ eksw, ushort_t* __restrict__ evsw, ushort_t* __restrict__ easw,
    const int* __restrict__ bidx, const int* __restrict__ hidx,
    int* __restrict__ cnt, int nqb, int E)
{
    __shared__ float xs[2][D][20];
    const int t  = threadIdx.x;
    const int nq = 3 * nqb;

    if ((int)blockIdx.x < nq) {
        // ---------------- qkv GEMM: [Nx128]@[128x128], 32 rows/block --------
        const int which = blockIdx.x / nqb;
        const int r0    = (blockIdx.x % nqb) * 32;
        const float* X = (which == 0) ? key   : (which == 1) ? value   : query;
        const float* W = (which == 0) ? key_w : (which == 1) ? value_w : query_w;
        const float* bias = (which == 0) ? key_b : (which == 1) ? value_b : query_b;
        ushort_t* Y = (which == 0) ? k16 : (which == 1) ? v16 : q16;

        const int rg = t >> 7, j = t & 127;
        const int rbase = r0 + rg * 16;
        {
            float tmp[16];
            #pragma unroll
            for (int r = 0; r < 16; ++r) tmp[r] = X[(size_t)(rbase + r) * D + j];
            #pragma unroll
            for (int c = 0; c < 4; ++c)
                *(float4*)&xs[rg][j][c * 4] = float4{tmp[c*4], tmp[c*4+1], tmp[c*4+2], tmp[c*4+3]};
        }
        __syncthreads();
        float acc[16];
        const float b = bias[j];
        #pragma unroll
        for (int r = 0; r < 16; ++r) acc[r] = b;
        #pragma unroll 4
        for (int i = 0; i < D; ++i) {
            const float w = W[i * D + j];
            #pragma unroll
            for (int c = 0; c < 4; ++c) {
                const float4 x4 = *(const float4*)&xs[rg][i][c * 4];
                acc[c*4+0] = fmaf(x4.x, w, acc[c*4+0]);
                acc[c*4+1] = fmaf(x4.y, w, acc[c*4+1]);
                acc[c*4+2] = fmaf(x4.z, w, acc[c*4+2]);
                acc[c*4+3] = fmaf(x4.w, w, acc[c*4+3]);
            }
        }
        #pragma unroll
        for (int r = 0; r < 16; ++r) Y[(size_t)(rbase + r) * D + j] = f2bf(acc[r]);
        return;
    }

    const int b2 = blockIdx.x - nq;
    if (b2 < 17) {
        // ---------------- w2 swizzle --------------------------------------
        const int g = b2 * 256 + t;
        const float* src; ushort_t* dst; int frag, ncols, nvalid;
        if (g < 2048)      { src = ekw2; dst = eksw; frag = g;        ncols = 128; nvalid = 128; }
        else if (g < 4096) { src = evw2; dst = evsw; frag = g - 2048; ncols = 128; nvalid = 128; }
        else if (g < 4352) { src = eaw2; dst = easw; frag = g - 4096; ncols = 8;   nvalid = 8; }
        else return;
        const int s = (frag >> 6) & 3;
        const int l = frag & 63;
        const int n = ((frag >> 8) << 4) + (l & 15);
        Pk8 pk;
        #pragma unroll
        for (int j = 0; j < 8; ++j) {
            const int k = s * 32 + (l >> 4) * 8 + j;
            const float v = (n < nvalid) ? src[k * ncols + n] : 0.f;
            pk.u[j] = f2bf(v);
        }
        *(uint4*)(dst + (size_t)frag * 8) = pk.v;
        return;
    }

    // ---------------- histogram ------------------------------------------
    const int e = (b2 - 17) * 256 + t;
    if (e < E) atomicAdd(&cnt[bidx[e] * LSEQ + hidx[e]], 1);
}

// ---------------------------------------------------------------------------
// Exclusive scan of the 16384-bin histogram (single block).
// ---------------------------------------------------------------------------
__global__ __launch_bounds__(1024) void scan16k(
    const int* __restrict__ cnt, int* __restrict__ base)
{
    __shared__ int part[1024];
    const int t = threadIdx.x;
    int v[16], ex[16], s = 0;
    #pragma unroll
    for (int i = 0; i < 16; ++i) v[i] = cnt[t * 16 + i];
    #pragma unroll
    for (int i = 0; i < 16; ++i) { ex[i] = s; s += v[i]; }
    part[t] = s;
    __syncthreads();
    for (int off = 1; off < 1024; off <<= 1) {
        const int x = (t >= off) ? part[t - off] : 0;
        __syncthreads();
        part[t] += x;
        __syncthreads();
    }
    const int boff = (t > 0) ? part[t - 1] : 0;
    #pragma unroll
    for (int i = 0; i < 16; ++i) base[t * 16 + i] = boff + ex[i];
    if (t == 1023) base[NNODE] = boff + s;
}

// ---------------------------------------------------------------------------
// Final projection: Y = y @ W + b
// ---------------------------------------------------------------------------
__global__ __launch_bounds__(128) void out_gemm(
    const float* __restrict__ num, const float* __restrict__ W,
    const float* __restrict__ bias, float* __restrict__ Y)
{
    __shared__ float xs[D][20];
    const int j  = threadIdx.x;
    const int r0 = blockIdx.x * 16;
    {
        float tmp[16];
        #pragma unroll
        for (int r = 0; r < 16; ++r) tmp[r] = num[(size_t)(r0 + r) * D + j];
        #pragma unroll
        for (int c = 0; c < 4; ++c)
            *(float4*)&xs[j][c * 4] = float4{tmp[c*4], tmp[c*4+1], tmp[c*4+2], tmp[c*4+3]};
    }
    __syncthreads();
    float acc[16];
    const float b = bias[j];
    #pragma unroll
    for (int r = 0; r < 16; ++r) acc[r] = b;
    #pragma unroll 4
    for (int i = 0; i < D; ++i) {
        const float w = W[i * D + j];
        #pragma unroll
        for (int c = 0; c < 4; ++c) {
            const float4 x4 = *(const float4*)&xs[i][c * 4];
            acc[c*4+0] = fmaf(x4.x, w, acc[c*4+0]);
            acc[c*4+1] = fmaf(x4.y, w, acc[c*4+1]);
            acc[c*4+2] = fmaf(x4.z, w, acc[c*4+2]);
            acc[c*4+3] = fmaf(x4.w, w, acc[c*4+3]);
        }
    }
    #pragma unroll
    for (int r = 0; r < 16; ++r) Y[(size_t)(r0 + r) * D + j] = acc[r];
}

// ---------------------------------------------------------------------------
// Fused edge kernel — barrier-free wave-local pipeline, bf16 k/q/v gathers,
// also writes this block's CSR order slots. No inter-wave deps after preload.
// ---------------------------------------------------------------------------
__global__ __launch_bounds__(256, 4) void edge_kernel(
    const float* __restrict__ edge_feats,
    const int* __restrict__ bidx, const int* __restrict__ hidx, const int* __restrict__ tidx,
    const float* __restrict__ ea_w1, const float* __restrict__ ea_b1,
    const float* __restrict__ ea_g,  const float* __restrict__ ea_be, const float* __restrict__ ea_b2,
    const float* __restrict__ ek_w1, const float* __restrict__ ek_b1,
    const float* __restrict__ ek_g,  const float* __restrict__ ek_be, const float* __restrict__ ek_b2,
    const float* __restrict__ ev_w1, const float* __restrict__ ev_b1,
    const float* __restrict__ ev_g,  const float* __restrict__ ev_be, const float* __restrict__ ev_b2,
    const ushort_t* __restrict__ easw, const ushort_t* __restrict__ eksw, const ushort_t* __restrict__ evsw,
    const ushort_t* __restrict__ k16, const ushort_t* __restrict__ q16, const ushort_t* __restrict__ v16,
    const int* __restrict__ base, int* __restrict__ cnt, int* __restrict__ order,
    float* __restrict__ ex_ws, ushort_t* __restrict__ vs_ws)
{
    __shared__ float pw1[3][FE * D];
    __shared__ float pb1[3][D], pg[3][D], pbe[3][D];
    __shared__ float pb2k[D], pb2v[D], pb2a[NHEAD];
    __shared__ float ef_s[EPB][FE];
    __shared__ int   eh_s[EPB], et_s[EPB];

    const int t   = threadIdx.x;
    const int e0g = blockIdx.x * EPB;

    for (int i = t; i < FE * D; i += 256) { pw1[0][i] = ea_w1[i]; pw1[1][i] = ek_w1[i]; pw1[2][i] = ev_w1[i]; }
    if (t < D) {
        pb1[0][t] = ea_b1[t]; pb1[1][t] = ek_b1[t]; pb1[2][t] = ev_b1[t];
        pg [0][t] = ea_g [t]; pg [1][t] = ek_g [t]; pg [2][t] = ev_g [t];
        pbe[0][t] = ea_be[t]; pbe[1][t] = ek_be[t]; pbe[2][t] = ev_be[t];
        pb2k[t] = ek_b2[t];   pb2v[t] = ev_b2[t];
        if (t < NHEAD) pb2a[t] = ea_b2[t];
    }
    for (int i = t; i < EPB * FE; i += 256) ((float*)ef_s)[i] = edge_feats[(size_t)e0g * FE + i];
    if (t < EPB) {
        const int bb = bidx[e0g + t];
        const int nh = bb * LSEQ + hidx[e0g + t];
        eh_s[t] = nh;
        et_s[t] = bb * LSEQ + tidx[e0g + t];
        // fused CSR scatter_order for this block's edges
        const int slot = atomicSub(&cnt[nh], 1) - 1;
        order[base[nh] + slot] = e0g + t;
    }
    __syncthreads();     // the only barrier

    const int mt   = t >> 6;        // wave id == m-tile
    const int l    = t & 63;        // lane
    const int qt   = l & 3;         // producer: dim-chunk quarter
    const int per  = l >> 2;        // producer: edge row 0..15
    const int row0 = (l >> 4) * 4;  // consumer: accumulator row base
    const int colb = l & 15;        // consumer: column within n-tile
    const int src  = 4 * colb + (l >> 4);   // shfl source for A-frag chunks
    const int bsrc = (l & 48);      // row-group base for ea broadcasts

    int tn[4], hnn[4];
    #pragma unroll
    for (int r = 0; r < 4; ++r) { tn[r] = et_s[mt*16 + row0 + r]; hnn[r] = eh_s[mt*16 + row0 + r]; }

    float efr[FE];
    #pragma unroll
    for (int f = 0; f < FE; ++f) efr[f] = ef_s[mt*16 + per][f];

    auto first_layer = [&](int m, uint4 pk[4]) {
        const float4* w1v = (const float4*)&pw1[m][0];
        const float4* b1v = (const float4*)&pb1[m][0];
        const float4* gv  = (const float4*)&pg[m][0];
        const float4* bev = (const float4*)&pbe[m][0];
        float4 hv[4][2];
        float s1 = 0.f, s2 = 0.f;
        #pragma unroll
        for (int s = 0; s < 4; ++s) {
            #pragma unroll
            for (int hc = 0; hc < 2; ++hc) {
                const int idx = s * 8 + qt * 2 + hc;
                float4 a = b1v[idx];
                #pragma unroll
                for (int f = 0; f < FE; ++f) {
                    const float sc = efr[f];
                    const float4 w = w1v[f * 32 + idx];
                    a.x = fmaf(sc, w.x, a.x); a.y = fmaf(sc, w.y, a.y);
                    a.z = fmaf(sc, w.z, a.z); a.w = fmaf(sc, w.w, a.w);
                }
                a.x = fmaxf(a.x, 0.f); a.y = fmaxf(a.y, 0.f);
                a.z = fmaxf(a.z, 0.f); a.w = fmaxf(a.w, 0.f);
                hv[s][hc] = a;
                s1 += a.x + a.y + a.z + a.w;
                s2 += a.x*a.x + a.y*a.y + a.z*a.z + a.w*a.w;
            }
        }
        s1 += __shfl_xor(s1, 1); s1 += __shfl_xor(s1, 2);
        s2 += __shfl_xor(s2, 1); s2 += __shfl_xor(s2, 2);
        const float mu = s1 * (1.f / 128.f);
        const float rs = rsqrtf(s2 * (1.f / 128.f) - mu * mu + EPS_LN);
        #pragma unroll
        for (int s = 0; s < 4; ++s) {
            const int idx = s * 8 + qt * 2;
            const float4 x0 = hv[s][0], x1 = hv[s][1];
            const float4 g0 = gv[idx], g1 = gv[idx + 1];
            const float4 b0 = bev[idx], b1 = bev[idx + 1];
            Pk8 p8;
            p8.u[0] = f2bf(fmaf((x0.x - mu) * rs, g0.x, b0.x));
            p8.u[1] = f2bf(fmaf((x0.y - mu) * rs, g0.y, b0.y));
            p8.u[2] = f2bf(fmaf((x0.z - mu) * rs, g0.z, b0.z));
            p8.u[3] = f2bf(fmaf((x0.w - mu) * rs, g0.w, b0.w));
            p8.u[4] = f2bf(fmaf((x1.x - mu) * rs, g1.x, b1.x));
            p8.u[5] = f2bf(fmaf((x1.y - mu) * rs, g1.y, b1.y));
            p8.u[6] = f2bf(fmaf((x1.z - mu) * rs, g1.z, b1.z));
            p8.u[7] = f2bf(fmaf((x1.w - mu) * rs, g1.w, b1.w));
            pk[s] = p8.v;
        }
    };

    auto gather_afr = [&](const uint4 pk[4], bf16x8 afr[4]) {
        #pragma unroll
        for (int s = 0; s < 4; ++s) {
            uint4 w;
            w.x = (unsigned)__shfl((int)pk[s].x, src);
            w.y = (unsigned)__shfl((int)pk[s].y, src);
            w.z = (unsigned)__shfl((int)pk[s].z, src);
            w.w = (unsigned)__shfl((int)pk[s].w, src);
            afr[s] = __builtin_bit_cast(bf16x8, w);
        }
    };

    uint4 pk[4];
    bf16x8 afr[4];

    // ================= MLP 0: ea (attention bias, cols padded 8->16) ========
    float eaacc[4];
    first_layer(0, pk);
    gather_afr(pk, afr);
    {
        f32x4 acc = {0.f, 0.f, 0.f, 0.f};
        #pragma unroll
        for (int s = 0; s < 4; ++s) {
            const bf16x8 bfr = *(const bf16x8*)(easw + (size_t)(s * 64 + l) * 8);
            acc = __builtin_amdgcn_mfma_f32_16x16x32_bf16(afr[s], bfr, acc, 0, 0, 0);
        }
        #pragma unroll
        for (int r = 0; r < 4; ++r) eaacc[r] = acc[r];   // raw; bias added later
    }

    // ================= MLP 1: ek -> scores -> exp -> ex_ws ==================
    first_layer(1, pk);
    gather_afr(pk, afr);
    #pragma unroll
    for (int nt = 0; nt < NHEAD; ++nt) {
        f32x4 acc = {0.f, 0.f, 0.f, 0.f};
        #pragma unroll
        for (int s = 0; s < 4; ++s) {
            const bf16x8 bfr = *(const bf16x8*)(eksw + (size_t)((nt * 4 + s) * 64 + l) * 8);
            acc = __builtin_amdgcn_mfma_f32_16x16x32_bf16(afr[s], bfr, acc, 0, 0, 0);
        }
        const int col = nt * 16 + colb;
        const float b2 = pb2k[col];
        const float ba = pb2a[nt];
        float pr[4];
        #pragma unroll
        for (int r = 0; r < 4; ++r)
            pr[r] = (acc[r] + b2 + bf2f(k16[(size_t)tn[r] * D + col]))
                    * bf2f(q16[(size_t)hnn[r] * D + col]);
        #pragma unroll
        for (int m = 1; m < 16; m <<= 1) {
            #pragma unroll
            for (int r = 0; r < 4; ++r) pr[r] += __shfl_xor(pr[r], m);
        }
        #pragma unroll
        for (int r = 0; r < 4; ++r) {
            // segment-max skipped: |score| small, exp cannot overflow.
            const float ea = __shfl(eaacc[r], bsrc | nt);
            const float ex = __expf(pr[r] + ea + ba);
            if (colb == nt)
                ex_ws[(size_t)(e0g + mt*16 + row0 + r) * NHEAD + nt] = ex;
        }
    }

    // ================= MLP 2: ev -> raw vs (bf16) ===========================
    first_layer(2, pk);
    gather_afr(pk, afr);
    #pragma unroll
    for (int nt = 0; nt < NHEAD; ++nt) {
        f32x4 acc = {0.f, 0.f, 0.f, 0.f};
        #pragma unroll
        for (int s = 0; s < 4; ++s) {
            const bf16x8 bfr = *(const bf16x8*)(evsw + (size_t)((nt * 4 + s) * 64 + l) * 8);
            acc = __builtin_amdgcn_mfma_f32_16x16x32_bf16(afr[s], bfr, acc, 0, 0, 0);
        }
        const int col = nt * 16 + colb;
        const float b2 = pb2v[col];
        #pragma unroll
        for (int r = 0; r < 4; ++r) {
            const float vs = acc[r] + b2 + bf2f(v16[(size_t)tn[r] * D + col]);
            vs_ws[(size_t)(e0g + mt*16 + row0 + r) * D + col] = f2bf(vs);
        }
    }
}

// ---------------------------------------------------------------------------
// Aggregation: one block per head node, walk CSR segment, no atomics.
// ---------------------------------------------------------------------------
__global__ __launch_bounds__(128) void agg_kernel(
    const int* __restrict__ order, const int* __restrict__ base,
    const float* __restrict__ ex_ws, const ushort_t* __restrict__ vs_ws,
    float* __restrict__ y_ws)
{
    const int n  = blockIdx.x;
    const int j  = threadIdx.x;
    const int h  = j >> 4;
    const int s0 = base[n], s1 = base[n + 1];

    float acc = 0.f, den = 0.f;
    int i = s0;
    for (; i + 8 <= s1; i += 8) {
        int e[8];
        #pragma unroll
        for (int r = 0; r < 8; ++r) e[r] = order[i + r];
        float exv[8], vsv[8];
        #pragma unroll
        for (int r = 0; r < 8; ++r) {
            exv[r] = ex_ws[(size_t)e[r] * NHEAD + h];
            vsv[r] = bf2f(vs_ws[(size_t)e[r] * D + j]);
        }
        #pragma unroll
        for (int r = 0; r < 8; ++r) {
            den += exv[r];
            acc = fmaf(exv[r], vsv[r], acc);
        }
    }
    for (; i < s1; ++i) {
        const int e = order[i];
        const float ex = ex_ws[(size_t)e * NHEAD + h];
        den += ex;
        acc = fmaf(ex, bf2f(vs_ws[(size_t)e * D + j]), acc);
    }
    y_ws[(size_t)n * D + j] = acc / (den + EPS_SM);
}

// ---------------------------------------------------------------------------
extern "C" void kernel_launch(void* const* d_in, const int* in_sizes, int n_in,
                              void* d_out, int out_size, void* d_ws, size_t ws_size,
                              hipStream_t stream)
{
    const float* key        = (const float*)d_in[0];
    const float* value      = (const float*)d_in[1];
    const float* query      = (const float*)d_in[2];
    const float* edge_feats = (const float*)d_in[3];
    const int*   bidx       = (const int*)d_in[5];
    const int*   hidx       = (const int*)d_in[6];
    const int*   tidx       = (const int*)d_in[7];
    const float* key_w   = (const float*)d_in[8];  const float* key_b   = (const float*)d_in[9];
    const float* query_w = (const float*)d_in[10]; const float* query_b = (const float*)d_in[11];
    const float* value_w = (const float*)d_in[12]; const float* value_b = (const float*)d_in[13];
    const float* proj_w  = (const float*)d_in[14]; const float* proj_b  = (const float*)d_in[15];

    const int N = in_sizes[0] / D;   // 16384 nodes
    const int E = in_sizes[5];       // 262144 edges

    char* ws = (char*)d_ws;
    ushort_t* k16   = (ushort_t*)ws; ws += (size_t)N * D * 2;
    ushort_t* q16   = (ushort_t*)ws; ws += (size_t)N * D * 2;
    ushort_t* v16   = (ushort_t*)ws; ws += (size_t)N * D * 2;
    float* y_ws     = (float*)ws;    ws += (size_t)N * D * 4;
    float* ex_ws    = (float*)ws;    ws += (size_t)E * NHEAD * 4;
    ushort_t* vs_ws = (ushort_t*)ws; ws += (size_t)E * D * 2;
    ushort_t* eksw  = (ushort_t*)ws; ws += (size_t)2048 * 8 * 2;
    ushort_t* evsw  = (ushort_t*)ws; ws += (size_t)2048 * 8 * 2;
    ushort_t* easw  = (ushort_t*)ws; ws += (size_t)256 * 8 * 2;
    int* order = (int*)ws;  ws += (size_t)E * 4;
    int* base  = (int*)ws;  ws += (size_t)(N + 1) * 4;
    int* cnt   = (int*)ws;  ws += (size_t)N * 4;

    const int nqb = N / 32;               // qkv blocks per matrix (512)
    const int nhist = (E + 255) / 256;    // 1024
    const int ngrid = 3 * nqb + 17 + nhist;

    hipMemsetAsync(cnt, 0, (size_t)N * 4, stream);

    setup_kernel<<<ngrid, 256, 0, stream>>>(
        key, value, query,
        key_w, key_b, value_w, value_b, query_w, query_b,
        k16, v16, q16,
        (const float*)d_in[26], (const float*)d_in[32], (const float*)d_in[20],
        eksw, evsw, easw,
        bidx, hidx, cnt, nqb, E);

    scan16k<<<1, 1024, 0, stream>>>(cnt, base);

    edge_kernel<<<E / EPB, 256, 0, stream>>>(
        edge_feats, bidx, hidx, tidx,
        (const float*)d_in[16], (const float*)d_in[17], (const float*)d_in[18],
        (const float*)d_in[19], (const float*)d_in[21],
        (const float*)d_in[22], (const float*)d_in[23], (const float*)d_in[24],
        (const float*)d_in[25], (const float*)d_in[27],
        (const float*)d_in[28], (const float*)d_in[29], (const float*)d_in[30],
        (const float*)d_in[31], (const float*)d_in[33],
        easw, eksw, evsw,
        k16, q16, v16,
        base, cnt, order,
        ex_ws, vs_ws);

    agg_kernel<<<N, 128, 0, stream>>>(order, base, ex_ws, vs_ws, y_ws);

    out_gemm<<<N / 16, 128, 0, stream>>>(y_ws, proj_w, proj_b, (float*)d_out);
}